// Round 1
// baseline (1697.427 us; speedup 1.0000x reference)
//
#include <hip/hip_runtime.h>
#include <math.h>

#define BB 64
#define T_FR 200
#define NA 48000
#define NBINS 24001

// ---------------- conv1: in (B,129,200) [cond + voiced], w (256,129,5), pad 2 ----------------
__global__ void conv1_kernel(const float* __restrict__ cond, const float* __restrict__ f0,
                             const float* __restrict__ w, const float* __restrict__ bias,
                             float* __restrict__ out)
{
    __shared__ float ws[129 * 5];
    int o = blockIdx.x, b = blockIdx.y;
    for (int j = threadIdx.x; j < 129 * 5; j += 256) ws[j] = w[o * 129 * 5 + j];
    __syncthreads();
    int t = threadIdx.x;
    if (t >= 200) return;
    float acc = bias[o];
    const float* cb = cond + (size_t)b * 128 * 200;
    for (int i = 0; i < 128; ++i) {
        const float* row = cb + i * 200;
        const float* wr = ws + i * 5;
#pragma unroll
        for (int k = 0; k < 5; ++k) {
            int tt = t + k - 2;
            if (tt >= 0 && tt < 200) acc += row[tt] * wr[k];
        }
    }
    {
        const float* wr = ws + 128 * 5;
        const float* fb = f0 + b * 200;
#pragma unroll
        for (int k = 0; k < 5; ++k) {
            int tt = t + k - 2;
            if (tt >= 0 && tt < 200) acc += ((fb[tt] > 0.f) ? 1.f : 0.f) * wr[k];
        }
    }
    acc = acc >= 0.f ? acc : 0.1f * acc;
    out[((size_t)b * 256 + o) * 200 + t] = acc;
}

// ---------------- conv k=3 pad=1, leaky ----------------
template<int CIN>
__global__ void conv3x_kernel(const float* __restrict__ in, const float* __restrict__ w,
                              const float* __restrict__ bias, float* __restrict__ out, int Cout)
{
    __shared__ float ws[CIN * 3];
    int o = blockIdx.x, b = blockIdx.y;
    for (int j = threadIdx.x; j < CIN * 3; j += 256) ws[j] = w[o * CIN * 3 + j];
    __syncthreads();
    int t = threadIdx.x;
    if (t >= 200) return;
    float acc = bias[o];
    const float* ib = in + (size_t)b * CIN * 200;
    for (int i = 0; i < CIN; ++i) {
        const float* row = ib + i * 200;
        const float* wr = ws + i * 3;
        float a0 = (t >= 1) ? row[t - 1] : 0.f;
        float a1 = row[t];
        float a2 = (t < 199) ? row[t + 1] : 0.f;
        acc += a0 * wr[0] + a1 * wr[1] + a2 * wr[2];
    }
    acc = acc >= 0.f ? acc : 0.1f * acc;
    out[((size_t)b * Cout + o) * 200 + t] = acc;
}

// ---------------- head: conv4 (40x64 k1) + sigmoid/softmax + avg_shape + outputs ----------------
__global__ void head_kernel(const float* __restrict__ h3, const float* __restrict__ w4,
                            const float* __restrict__ b4, float* __restrict__ control,
                            float* __restrict__ avg_shape, float* __restrict__ out_bf)
{
    __shared__ float w4s[40 * 64];
    __shared__ float b4s[40];
    __shared__ float sp[200 * 33];
    int b = blockIdx.x;
    for (int j = threadIdx.x; j < 40 * 64; j += 256) w4s[j] = w4[j];
    if (threadIdx.x < 40) b4s[threadIdx.x] = b4[threadIdx.x];
    __syncthreads();
    int t = threadIdx.x;
    if (t < 200) {
        float p[40];
#pragma unroll
        for (int o = 0; o < 40; ++o) p[o] = b4s[o];
        const float* hb = h3 + (size_t)b * 64 * 200;
        for (int i = 0; i < 64; ++i) {
            float h = hb[i * 200 + t];
#pragma unroll
            for (int o = 0; o < 40; ++o) p[o] += h * w4s[o * 64 + i];
        }
        float inh = 1.f / (1.f + expf(-p[0]));
        float exh = 1.f / (1.f + expf(-p[1]));
        float pr  = 1.f / (1.f + expf(-p[2]));
        // softmax over 32 spectral channels
        float mx = p[3];
#pragma unroll
        for (int c = 1; c < 32; ++c) mx = fmaxf(mx, p[3 + c]);
        float e[32];
        float sum = 0.f;
#pragma unroll
        for (int c = 0; c < 32; ++c) { e[c] = expf(p[3 + c] - mx); sum += e[c]; }
        float inv = 1.f / sum;
#pragma unroll
        for (int c = 0; c < 32; ++c) sp[t * 33 + c] = e[c] * inv;
        // softmax over 5 turbulence channels
        float mx2 = p[35];
#pragma unroll
        for (int c = 1; c < 5; ++c) mx2 = fmaxf(mx2, p[35 + c]);
        float e2[5];
        float s2 = 0.f;
#pragma unroll
        for (int c = 0; c < 5; ++c) { e2[c] = expf(p[35 + c] - mx2); s2 += e2[c]; }
        float inv2 = 1.f / s2;
        float* ctl = control + (size_t)b * 8 * 200;
        ctl[0 * 200 + t] = inh;
        ctl[1 * 200 + t] = exh;
        ctl[2 * 200 + t] = pr;
#pragma unroll
        for (int c = 0; c < 5; ++c) ctl[(3 + c) * 200 + t] = e2[c] * inv2;
        float* bf = out_bf + (size_t)b * 3 * 200;
        bf[0 * 200 + t] = pr;
        bf[1 * 200 + t] = inh;
        bf[2 * 200 + t] = exh;
    }
    __syncthreads();
    if (t < 32) {
        float s = 0.f;
        for (int j = 0; j < 200; ++j) s += sp[j * 33 + t];
        avg_shape[b * 32 + t] = s * (1.f / 200.f);
    }
}

// ---------------- loc_w[b,c] = mean over audio of interp(turb[b,c]) ----------------
__global__ void locw_kernel(const float* __restrict__ control, float* __restrict__ loc_w)
{
    int c = blockIdx.x, b = blockIdx.y;
    const float* src = control + ((size_t)b * 8 + 3 + c) * 200;
    float s = 0.f;
    for (int i = threadIdx.x; i < NA; i += 256) {
        float sf = (i + 0.5f) * (200.0f / 48000.0f) - 0.5f;
        sf = fminf(fmaxf(sf, 0.f), 199.f);
        int i0 = (int)sf;
        int i1 = min(i0 + 1, 199);
        float w = sf - (float)i0;
        s += src[i0] * (1.f - w) + src[i1] * w;
    }
    __shared__ float red[256];
    red[threadIdx.x] = s;
    __syncthreads();
    for (int st = 128; st > 0; st >>= 1) {
        if (threadIdx.x < st) red[threadIdx.x] += red[threadIdx.x + st];
        __syncthreads();
    }
    if (threadIdx.x == 0) loc_w[b * 5 + c] = red[0] * (1.f / 48000.f);
}

// ---------------- fbins: interp of the 5 analytic filter shapes to 24001 bins ----------------
__device__ inline float filter_shape_val(int c, int i)
{
    float lin = (float)i * (1.f / 31.f);
    if (c == 0) { float z = (lin - 0.2f) * 10.f;          return expf(-0.5f * z * z); }
    if (c == 1) { float z = (lin - 0.1f) * 10.f;          return expf(-0.5f * z * z); }
    if (c == 2) { float z = (lin - 0.4f) * (1.f / 0.15f); return expf(-0.5f * z * z); }
    if (c == 3) { float z = (lin - 0.6f) * 10.f;          return expf(-0.5f * z * z); }
    float v = 0.1f + 0.9f * lin;
    return v * v;
}

__global__ void fbins_kernel(float* __restrict__ fbins)
{
    int k = blockIdx.x * 256 + threadIdx.x;
    if (k >= NBINS) return;
    float sf = (k + 0.5f) * (32.0f / 24001.0f) - 0.5f;
    sf = fminf(fmaxf(sf, 0.f), 31.f);
    int i0 = (int)sf;
    int i1 = min(i0 + 1, 31);
    float w = sf - (float)i0;
#pragma unroll
    for (int c = 0; c < 5; ++c)
        fbins[c * NBINS + k] = filter_shape_val(c, i0) * (1.f - w) + filter_shape_val(c, i1) * w;
}

// ---------------- FFT: Stockham mixed-radix stage, out-of-place x->y ----------------
// y[q + s*(R*p + rp)] = sum_r x[q + s*p + (N/R)*r] * e^{sign*2pi*i*(p*rp/n + r*rp/R)}
template<int R>
__global__ void fft_stage(const float2* __restrict__ x, float2* __restrict__ y,
                          int n, int s, float sign)
{
    const int work = NA / R;
    int tid = blockIdx.x * 256 + threadIdx.x;
    if (tid >= work) return;
    int b = blockIdx.y;
    int p = tid / s;
    int q = tid - p * s;
    const float2* xb = x + (size_t)b * NA;
    float2* yb = y + (size_t)b * NA;
    float2 v[R];
    int base = q + s * p;
#pragma unroll
    for (int r = 0; r < R; ++r) v[r] = xb[base + work * r];
    int obase = q + s * R * p;
    float fn = 1.f / (float)n;
    for (int rp = 0; rp < R; ++rp) {
        int a = (p * rp) % n;
        float f1 = (float)a * fn;
        float re = 0.f, im = 0.f;
#pragma unroll
        for (int r = 0; r < R; ++r) {
            int bb = (r * rp) % R;
            float ph = sign * 2.f * (f1 + (float)bb * (1.f / (float)R));
            float sn, cs;
            sincospif(ph, &sn, &cs);
            re += v[r].x * cs - v[r].y * sn;
            im += v[r].x * sn + v[r].y * cs;
        }
        yb[obase + s * rp] = make_float2(re, im);
    }
}

// ---------------- elementwise helpers ----------------
__global__ void pack_real(const float* __restrict__ x, float2* __restrict__ A)
{
    size_t idx = (size_t)blockIdx.x * 256 + threadIdx.x;
    if (idx >= (size_t)BB * NA) return;
    A[idx] = make_float2(x[idx], 0.f);
}

__global__ void mul_gains(float2* __restrict__ A, const float* __restrict__ avg_shape)
{
    int i = blockIdx.x * 256 + threadIdx.x;
    int b = blockIdx.y;
    if (i >= NA) return;
    int kb = min(i, NA - i);
    int j = (kb * 32) / NBINS;
    if (j < 31 && (NBINS * (j + 1)) / 32 <= kb) ++j;
    float g = avg_shape[b * 32 + j] * (1.f / (float)NA);
    size_t idx = (size_t)b * NA + i;
    float2 v = A[idx];
    A[idx] = make_float2(v.x * g, v.y * g);
}

__global__ void std_kernel(const float2* __restrict__ A, float* __restrict__ scale)
{
    int b = blockIdx.x;
    float s = 0.f, s2 = 0.f;
    const float2* ab = A + (size_t)b * NA;
    for (int i = threadIdx.x; i < NA; i += 256) {
        float v = ab[i].x;
        s += v;
        s2 += v * v;
    }
    __shared__ float r1[256], r2[256];
    r1[threadIdx.x] = s;
    r2[threadIdx.x] = s2;
    __syncthreads();
    for (int st = 128; st > 0; st >>= 1) {
        if (threadIdx.x < st) {
            r1[threadIdx.x] += r1[threadIdx.x + st];
            r2[threadIdx.x] += r2[threadIdx.x + st];
        }
        __syncthreads();
    }
    if (threadIdx.x == 0) {
        float sum = r1[0], sumsq = r2[0];
        float var = (sumsq - sum * sum / (float)NA) / (float)(NA - 1);
        scale[b] = 0.1f / sqrtf(var);
    }
}

__global__ void mod_kernel(float2* __restrict__ A, const float* __restrict__ control,
                           const float* __restrict__ f0, const float* __restrict__ scale)
{
    int i = blockIdx.x * 256 + threadIdx.x;
    int b = blockIdx.y;
    if (i >= NA) return;
    float sf = (i + 0.5f) * (200.0f / 48000.0f) - 0.5f;
    sf = fminf(fmaxf(sf, 0.f), 199.f);
    int i0 = (int)sf;
    int i1 = min(i0 + 1, 199);
    float w = sf - (float)i0;
    const float* ctl = control + (size_t)b * 8 * 200;
    float inh = ctl[i0] * (1.f - w) + ctl[i1] * w;
    float exh = ctl[200 + i0] * (1.f - w) + ctl[200 + i1] * w;
    float pr  = ctl[400 + i0] * (1.f - w) + ctl[400 + i1] * w;
    const float* fb = f0 + b * 200;
    float v0 = fb[i0] > 0.f ? 1.f : 0.f;
    float v1 = fb[i1] > 0.f ? 1.f : 0.f;
    float vv = v0 * (1.f - w) + v1 * w;
    float m = inh * (1.f - vv) + exh * pr;
    size_t idx = (size_t)b * NA + i;
    float sh = A[idx].x * scale[b];
    A[idx] = make_float2(sh * m, 0.f);
}

__global__ void mul_filter(float2* __restrict__ A, const float* __restrict__ fbins,
                           const float* __restrict__ loc_w)
{
    int i = blockIdx.x * 256 + threadIdx.x;
    int b = blockIdx.y;
    if (i >= NA) return;
    int kb = min(i, NA - i);
    float tf = 0.f;
#pragma unroll
    for (int c = 0; c < 5; ++c) tf += loc_w[b * 5 + c] * fbins[c * NBINS + kb];
    tf *= (1.f / (float)NA);
    size_t idx = (size_t)b * NA + i;
    float2 v = A[idx];
    A[idx] = make_float2(v.x * tf, v.y * tf);
}

__global__ void unpack_real(const float2* __restrict__ A, float* __restrict__ out)
{
    size_t idx = (size_t)blockIdx.x * 256 + threadIdx.x;
    if (idx >= (size_t)BB * NA) return;
    out[idx] = A[idx].x;
}

// ---------------- host-side FFT driver (enqueue only; capture-safe) ----------------
static void run_fft(float2* A, float2* Bf, float sign, hipStream_t stream)
{
    struct St { int R, n, s; };
    const St st[6] = { {8, 48000, 1}, {8, 6000, 8}, {6, 750, 64},
                       {5, 125, 384}, {5, 25, 1920}, {5, 5, 9600} };
    float2* x = A;
    float2* y = Bf;
    for (int i = 0; i < 6; ++i) {
        int work = NA / st[i].R;
        dim3 grid((work + 255) / 256, BB);
        if (st[i].R == 8)      fft_stage<8><<<grid, 256, 0, stream>>>(x, y, st[i].n, st[i].s, sign);
        else if (st[i].R == 6) fft_stage<6><<<grid, 256, 0, stream>>>(x, y, st[i].n, st[i].s, sign);
        else                   fft_stage<5><<<grid, 256, 0, stream>>>(x, y, st[i].n, st[i].s, sign);
        float2* t = x; x = y; y = t;
    }
    // 6 stages (even) -> result back in A
}

extern "C" void kernel_launch(void* const* d_in, const int* in_sizes, int n_in,
                              void* d_out, int out_size, void* d_ws, size_t ws_size,
                              hipStream_t stream)
{
    const float* cond = (const float*)d_in[0];
    const float* f0   = (const float*)d_in[1];
    const float* wn   = (const float*)d_in[2];
    const float* w1   = (const float*)d_in[3];
    const float* b1   = (const float*)d_in[4];
    const float* w2   = (const float*)d_in[5];
    const float* b2   = (const float*)d_in[6];
    const float* w3   = (const float*)d_in[7];
    const float* b3   = (const float*)d_in[8];
    const float* w4   = (const float*)d_in[9];
    const float* b4   = (const float*)d_in[10];

    float* out = (float*)d_out;
    float* filtered = out;                       // B*NA
    float* bf_out   = out + (size_t)BB * NA;     // B*3*200

    char* ws = (char*)d_ws;
    float2* Abuf = (float2*)ws;                                  // 24,576,000 B
    float2* Bbuf = (float2*)(ws + (size_t)24576000);             // 24,576,000 B
    // h1/h2/h3 alias inside Bbuf: conv phase completes before FFT stage 1 writes Bbuf
    float* h1 = (float*)Bbuf;                // 3,276,800 floats
    float* h2 = h1 + 3276800;                // 1,638,400 floats
    float* h3 = h2 + 1638400;                //   819,200 floats  (total 5.73M < 6.14M)
    float* tail      = (float*)(ws + (size_t)49152000);
    float* control   = tail;                 // 64*8*200 = 102,400
    float* avg_shape = control + 102400;     // 64*32 = 2,048
    float* loc_w     = avg_shape + 2048;     // 320
    float* scale     = loc_w + 320;          // 64
    float* fbins     = scale + 64;           // 5*24001 = 120,005

    dim3 blk(256);

    // conv stack
    conv1_kernel<<<dim3(256, BB), blk, 0, stream>>>(cond, f0, w1, b1, h1);
    conv3x_kernel<256><<<dim3(128, BB), blk, 0, stream>>>(h1, w2, b2, h2, 128);
    conv3x_kernel<128><<<dim3(64, BB), blk, 0, stream>>>(h2, w3, b3, h3, 64);
    head_kernel<<<dim3(BB), blk, 0, stream>>>(h3, w4, b4, control, avg_shape, bf_out);
    locw_kernel<<<dim3(5, BB), blk, 0, stream>>>(control, loc_w);
    fbins_kernel<<<dim3((NBINS + 255) / 256), blk, 0, stream>>>(fbins);

    // pass 1: shape white noise in frequency domain
    pack_real<<<dim3((BB * NA + 255) / 256), blk, 0, stream>>>(wn, Abuf);
    run_fft(Abuf, Bbuf, -1.f, stream);
    mul_gains<<<dim3((NA + 255) / 256, BB), blk, 0, stream>>>(Abuf, avg_shape);
    run_fft(Abuf, Bbuf, +1.f, stream);

    // normalize + modulate
    std_kernel<<<dim3(BB), blk, 0, stream>>>(Abuf, scale);
    mod_kernel<<<dim3((NA + 255) / 256, BB), blk, 0, stream>>>(Abuf, control, f0, scale);

    // pass 2: turbulence filter
    run_fft(Abuf, Bbuf, -1.f, stream);
    mul_filter<<<dim3((NA + 255) / 256, BB), blk, 0, stream>>>(Abuf, fbins, loc_w);
    run_fft(Abuf, Bbuf, +1.f, stream);

    unpack_real<<<dim3((BB * NA + 255) / 256), blk, 0, stream>>>(Abuf, filtered);
}

// Round 2
// 887.773 us; speedup vs baseline: 1.9120x; 1.9120x over previous
//
#include <hip/hip_runtime.h>
#include <math.h>

#define BB 64
#define T_FR 200
#define NA 48000
#define NBINS 24001

// ---------------- generic tiled conv1d (k=3 or 5, 'same' pad), leaky-relu ----------------
// block: (og, b). 32 output channels per block, 256 threads.
// thread: o_local = tid>>3 (0..31), tc = tid&7 -> t in [tc*25, tc*25+25)
// input staged in LDS in CHUNK-channel slabs; weights staged transposed for
// conflict-free broadcast; sliding window kept in registers.
template<int K, int CHUNK, bool VOICED>
__global__ __launch_bounds__(256) void convT_kernel(
    const float* __restrict__ in, const float* __restrict__ f0,
    const float* __restrict__ w, const float* __restrict__ bias,
    float* __restrict__ out, int Cin, int Cout)
{
    constexpr int HALO = K / 2;
    constexpr int W = 25 + 2 * HALO;
    __shared__ float xs[CHUNK][208];
    __shared__ float wst[CHUNK * K * 32];
    const int og = blockIdx.x, b = blockIdx.y;
    const int tid = threadIdx.x;
    const int o_local = tid >> 3;
    const int tc = tid & 7;
    const int t0 = tc * 25;
    const int o = og * 32 + o_local;
    const int Creal = VOICED ? (Cin - 1) : Cin;

    float acc[25];
#pragma unroll
    for (int j = 0; j < 25; ++j) acc[j] = 0.f;

    const int nch = (Cin + CHUNK - 1) / CHUNK;
    for (int ci = 0; ci < nch; ++ci) {
        const int c0 = ci * CHUNK;
        const int cc = min(CHUNK, Cin - c0);
        __syncthreads();
        // stage input slab (coalesced; voiced channel synthesized from f0)
        for (int idx = tid; idx < cc * 200; idx += 256) {
            int ii = idx / 200;
            int t = idx - ii * 200;
            int gi = c0 + ii;
            float v;
            if (VOICED && gi == Cin - 1)
                v = (f0[b * 200 + t] > 0.f) ? 1.f : 0.f;
            else
                v = in[((size_t)b * Creal + gi) * 200 + t];
            xs[ii][t + HALO] = v;
        }
        // zero halos
        if (tid < CHUNK * 2 * HALO) {
            int ii = tid / (2 * HALO);
            int h = tid % (2 * HALO);
            xs[ii][(h < HALO) ? h : (200 + h)] = 0.f;
        }
        // stage weights transposed: wst[(ii*K+k)*32 + o]
        for (int idx = tid; idx < cc * K * 32; idx += 256) {
            int o2 = idx & 31;
            int rest = idx >> 5;
            int k = rest % K;
            int ii = rest / K;
            wst[(ii * K + k) * 32 + o2] =
                w[((size_t)(og * 32 + o2) * Cin + (c0 + ii)) * K + k];
        }
        __syncthreads();
        for (int ii = 0; ii < cc; ++ii) {
            float xr[W];
#pragma unroll
            for (int j = 0; j < W; ++j) xr[j] = xs[ii][t0 + j];
            float wr[K];
#pragma unroll
            for (int k = 0; k < K; ++k) wr[k] = wst[(ii * K + k) * 32 + o_local];
#pragma unroll
            for (int j = 0; j < 25; ++j) {
#pragma unroll
                for (int k = 0; k < K; ++k) acc[j] += xr[j + k] * wr[k];
            }
        }
    }
    const float bz = bias[o];
    float* ob = out + ((size_t)b * Cout + o) * 200 + t0;
#pragma unroll
    for (int j = 0; j < 25; ++j) {
        float v = acc[j] + bz;
        ob[j] = (v >= 0.f) ? v : 0.1f * v;
    }
}

// ---------------- head: conv4 (40x64 k1) + sigmoid/softmax + avg_shape + outputs ----------------
__global__ void head_kernel(const float* __restrict__ h3, const float* __restrict__ w4,
                            const float* __restrict__ b4, float* __restrict__ control,
                            float* __restrict__ avg_shape, float* __restrict__ out_bf)
{
    __shared__ float w4s[40 * 64];
    __shared__ float b4s[40];
    __shared__ float sp[200 * 33];
    int b = blockIdx.x;
    for (int j = threadIdx.x; j < 40 * 64; j += 256) w4s[j] = w4[j];
    if (threadIdx.x < 40) b4s[threadIdx.x] = b4[threadIdx.x];
    __syncthreads();
    int t = threadIdx.x;
    if (t < 200) {
        float p[40];
#pragma unroll
        for (int o = 0; o < 40; ++o) p[o] = b4s[o];
        const float* hb = h3 + (size_t)b * 64 * 200;
        for (int i = 0; i < 64; ++i) {
            float h = hb[i * 200 + t];
#pragma unroll
            for (int o = 0; o < 40; ++o) p[o] += h * w4s[o * 64 + i];
        }
        float inh = 1.f / (1.f + expf(-p[0]));
        float exh = 1.f / (1.f + expf(-p[1]));
        float pr  = 1.f / (1.f + expf(-p[2]));
        float mx = p[3];
#pragma unroll
        for (int c = 1; c < 32; ++c) mx = fmaxf(mx, p[3 + c]);
        float e[32];
        float sum = 0.f;
#pragma unroll
        for (int c = 0; c < 32; ++c) { e[c] = expf(p[3 + c] - mx); sum += e[c]; }
        float inv = 1.f / sum;
#pragma unroll
        for (int c = 0; c < 32; ++c) sp[t * 33 + c] = e[c] * inv;
        float mx2 = p[35];
#pragma unroll
        for (int c = 1; c < 5; ++c) mx2 = fmaxf(mx2, p[35 + c]);
        float e2[5];
        float s2 = 0.f;
#pragma unroll
        for (int c = 0; c < 5; ++c) { e2[c] = expf(p[35 + c] - mx2); s2 += e2[c]; }
        float inv2 = 1.f / s2;
        float* ctl = control + (size_t)b * 8 * 200;
        ctl[0 * 200 + t] = inh;
        ctl[1 * 200 + t] = exh;
        ctl[2 * 200 + t] = pr;
#pragma unroll
        for (int c = 0; c < 5; ++c) ctl[(3 + c) * 200 + t] = e2[c] * inv2;
        float* bf = out_bf + (size_t)b * 3 * 200;
        bf[0 * 200 + t] = pr;
        bf[1 * 200 + t] = inh;
        bf[2 * 200 + t] = exh;
    }
    __syncthreads();
    if (t < 32) {
        float s = 0.f;
        for (int j = 0; j < 200; ++j) s += sp[j * 33 + t];
        avg_shape[b * 32 + t] = s * (1.f / 200.f);
    }
}

// ---------------- loc_w[b,c] = mean over audio of interp(turb[b,c]) ----------------
__global__ void locw_kernel(const float* __restrict__ control, float* __restrict__ loc_w)
{
    int c = blockIdx.x, b = blockIdx.y;
    const float* src = control + ((size_t)b * 8 + 3 + c) * 200;
    float s = 0.f;
    for (int i = threadIdx.x; i < NA; i += 256) {
        float sf = (i + 0.5f) * (200.0f / 48000.0f) - 0.5f;
        sf = fminf(fmaxf(sf, 0.f), 199.f);
        int i0 = (int)sf;
        int i1 = min(i0 + 1, 199);
        float w = sf - (float)i0;
        s += src[i0] * (1.f - w) + src[i1] * w;
    }
    __shared__ float red[256];
    red[threadIdx.x] = s;
    __syncthreads();
    for (int st = 128; st > 0; st >>= 1) {
        if (threadIdx.x < st) red[threadIdx.x] += red[threadIdx.x + st];
        __syncthreads();
    }
    if (threadIdx.x == 0) loc_w[b * 5 + c] = red[0] * (1.f / 48000.f);
}

// ---------------- fbins ----------------
__device__ inline float filter_shape_val(int c, int i)
{
    float lin = (float)i * (1.f / 31.f);
    if (c == 0) { float z = (lin - 0.2f) * 10.f;          return expf(-0.5f * z * z); }
    if (c == 1) { float z = (lin - 0.1f) * 10.f;          return expf(-0.5f * z * z); }
    if (c == 2) { float z = (lin - 0.4f) * (1.f / 0.15f); return expf(-0.5f * z * z); }
    if (c == 3) { float z = (lin - 0.6f) * 10.f;          return expf(-0.5f * z * z); }
    float v = 0.1f + 0.9f * lin;
    return v * v;
}

__global__ void fbins_kernel(float* __restrict__ fbins)
{
    int k = blockIdx.x * 256 + threadIdx.x;
    if (k >= NBINS) return;
    float sf = (k + 0.5f) * (32.0f / 24001.0f) - 0.5f;
    sf = fminf(fmaxf(sf, 0.f), 31.f);
    int i0 = (int)sf;
    int i1 = min(i0 + 1, 31);
    float w = sf - (float)i0;
#pragma unroll
    for (int c = 0; c < 5; ++c)
        fbins[c * NBINS + k] = filter_shape_val(c, i0) * (1.f - w) + filter_shape_val(c, i1) * w;
}

// ---------------- FFT: Stockham mixed-radix stage ----------------
// twiddle = wc(rp) * u[(r*rp)%R] with wc the power chain of e^{sign*2pi*p/n}
template<int R>
__global__ __launch_bounds__(256) void fft_stage(const float2* __restrict__ x,
                                                 float2* __restrict__ y,
                                                 int n, int s, float sign)
{
    const int work = NA / R;
    int tid = blockIdx.x * 256 + threadIdx.x;
    if (tid >= work) return;
    int b = blockIdx.y;
    int p = tid / s;
    int q = tid - p * s;
    const float2* xb = x + (size_t)b * NA;
    float2* yb = y + (size_t)b * NA;
    float2 v[R];
    int base = q + s * p;
#pragma unroll
    for (int r = 0; r < R; ++r) v[r] = xb[base + work * r];

    float2 u[R];
#pragma unroll
    for (int m = 0; m < R; ++m) {
        float sn, cs;
        sincospif(sign * 2.f * (float)m / (float)R, &sn, &cs);
        u[m] = make_float2(cs, sn);
    }
    float sn0, cs0;
    sincospif(sign * 2.f * (float)p / (float)n, &sn0, &cs0);
    float2 w0 = make_float2(cs0, sn0);
    float2 wc = make_float2(1.f, 0.f);

    int obase = q + s * R * p;
#pragma unroll
    for (int rp = 0; rp < R; ++rp) {
        float re = 0.f, im = 0.f;
#pragma unroll
        for (int r = 0; r < R; ++r) {
            int m = (r * rp) % R;
            re += v[r].x * u[m].x - v[r].y * u[m].y;
            im += v[r].x * u[m].y + v[r].y * u[m].x;
        }
        yb[obase + s * rp] = make_float2(re * wc.x - im * wc.y, re * wc.y + im * wc.x);
        wc = make_float2(wc.x * w0.x - wc.y * w0.y, wc.x * w0.y + wc.y * w0.x);
    }
}

// ---------------- elementwise helpers ----------------
__global__ void pack_real(const float* __restrict__ x, float2* __restrict__ A)
{
    size_t idx = (size_t)blockIdx.x * 256 + threadIdx.x;
    if (idx >= (size_t)BB * NA) return;
    A[idx] = make_float2(x[idx], 0.f);
}

__global__ void mul_gains(float2* __restrict__ A, const float* __restrict__ avg_shape)
{
    int i = blockIdx.x * 256 + threadIdx.x;
    int b = blockIdx.y;
    if (i >= NA) return;
    int kb = min(i, NA - i);
    int j = (kb * 32) / NBINS;
    if (j < 31 && (NBINS * (j + 1)) / 32 <= kb) ++j;
    float g = avg_shape[b * 32 + j] * (1.f / (float)NA);
    size_t idx = (size_t)b * NA + i;
    float2 v = A[idx];
    A[idx] = make_float2(v.x * g, v.y * g);
}

__global__ void std_kernel(const float2* __restrict__ A, float* __restrict__ scale)
{
    int b = blockIdx.x;
    float s = 0.f, s2 = 0.f;
    const float2* ab = A + (size_t)b * NA;
    for (int i = threadIdx.x; i < NA; i += 256) {
        float v = ab[i].x;
        s += v;
        s2 += v * v;
    }
    __shared__ float r1[256], r2[256];
    r1[threadIdx.x] = s;
    r2[threadIdx.x] = s2;
    __syncthreads();
    for (int st = 128; st > 0; st >>= 1) {
        if (threadIdx.x < st) {
            r1[threadIdx.x] += r1[threadIdx.x + st];
            r2[threadIdx.x] += r2[threadIdx.x + st];
        }
        __syncthreads();
    }
    if (threadIdx.x == 0) {
        float sum = r1[0], sumsq = r2[0];
        float var = (sumsq - sum * sum / (float)NA) / (float)(NA - 1);
        scale[b] = 0.1f / sqrtf(var);
    }
}

__global__ void mod_kernel(float2* __restrict__ A, const float* __restrict__ control,
                           const float* __restrict__ f0, const float* __restrict__ scale)
{
    int i = blockIdx.x * 256 + threadIdx.x;
    int b = blockIdx.y;
    if (i >= NA) return;
    float sf = (i + 0.5f) * (200.0f / 48000.0f) - 0.5f;
    sf = fminf(fmaxf(sf, 0.f), 199.f);
    int i0 = (int)sf;
    int i1 = min(i0 + 1, 199);
    float w = sf - (float)i0;
    const float* ctl = control + (size_t)b * 8 * 200;
    float inh = ctl[i0] * (1.f - w) + ctl[i1] * w;
    float exh = ctl[200 + i0] * (1.f - w) + ctl[200 + i1] * w;
    float pr  = ctl[400 + i0] * (1.f - w) + ctl[400 + i1] * w;
    const float* fb = f0 + b * 200;
    float v0 = fb[i0] > 0.f ? 1.f : 0.f;
    float v1 = fb[i1] > 0.f ? 1.f : 0.f;
    float vv = v0 * (1.f - w) + v1 * w;
    float m = inh * (1.f - vv) + exh * pr;
    size_t idx = (size_t)b * NA + i;
    float sh = A[idx].x * scale[b];
    A[idx] = make_float2(sh * m, 0.f);
}

__global__ void mul_filter(float2* __restrict__ A, const float* __restrict__ fbins,
                           const float* __restrict__ loc_w)
{
    int i = blockIdx.x * 256 + threadIdx.x;
    int b = blockIdx.y;
    if (i >= NA) return;
    int kb = min(i, NA - i);
    float tf = 0.f;
#pragma unroll
    for (int c = 0; c < 5; ++c) tf += loc_w[b * 5 + c] * fbins[c * NBINS + kb];
    tf *= (1.f / (float)NA);
    size_t idx = (size_t)b * NA + i;
    float2 v = A[idx];
    A[idx] = make_float2(v.x * tf, v.y * tf);
}

__global__ void unpack_real(const float2* __restrict__ A, float* __restrict__ out)
{
    size_t idx = (size_t)blockIdx.x * 256 + threadIdx.x;
    if (idx >= (size_t)BB * NA) return;
    out[idx] = A[idx].x;
}

// ---------------- host-side FFT driver ----------------
static void run_fft(float2* A, float2* Bf, float sign, hipStream_t stream)
{
    struct St { int R, n, s; };
    const St st[6] = { {8, 48000, 1}, {8, 6000, 8}, {6, 750, 64},
                       {5, 125, 384}, {5, 25, 1920}, {5, 5, 9600} };
    float2* x = A;
    float2* y = Bf;
    for (int i = 0; i < 6; ++i) {
        int work = NA / st[i].R;
        dim3 grid((work + 255) / 256, BB);
        if (st[i].R == 8)      fft_stage<8><<<grid, 256, 0, stream>>>(x, y, st[i].n, st[i].s, sign);
        else if (st[i].R == 6) fft_stage<6><<<grid, 256, 0, stream>>>(x, y, st[i].n, st[i].s, sign);
        else                   fft_stage<5><<<grid, 256, 0, stream>>>(x, y, st[i].n, st[i].s, sign);
        float2* t = x; x = y; y = t;
    }
}

extern "C" void kernel_launch(void* const* d_in, const int* in_sizes, int n_in,
                              void* d_out, int out_size, void* d_ws, size_t ws_size,
                              hipStream_t stream)
{
    const float* cond = (const float*)d_in[0];
    const float* f0   = (const float*)d_in[1];
    const float* wn   = (const float*)d_in[2];
    const float* w1   = (const float*)d_in[3];
    const float* b1   = (const float*)d_in[4];
    const float* w2   = (const float*)d_in[5];
    const float* b2   = (const float*)d_in[6];
    const float* w3   = (const float*)d_in[7];
    const float* b3   = (const float*)d_in[8];
    const float* w4   = (const float*)d_in[9];
    const float* b4   = (const float*)d_in[10];

    float* out = (float*)d_out;
    float* filtered = out;
    float* bf_out   = out + (size_t)BB * NA;

    char* ws = (char*)d_ws;
    float2* Abuf = (float2*)ws;
    float2* Bbuf = (float2*)(ws + (size_t)24576000);
    float* h1 = (float*)Bbuf;
    float* h2 = h1 + 3276800;
    float* h3 = h2 + 1638400;
    float* tail      = (float*)(ws + (size_t)49152000);
    float* control   = tail;
    float* avg_shape = control + 102400;
    float* loc_w     = avg_shape + 2048;
    float* scale     = loc_w + 320;
    float* fbins     = scale + 64;

    dim3 blk(256);

    // conv stack (tiled)
    convT_kernel<5, 16, true ><<<dim3(8, BB), blk, 0, stream>>>(cond, f0, w1, b1, h1, 129, 256);
    convT_kernel<3, 16, false><<<dim3(4, BB), blk, 0, stream>>>(h1, nullptr, w2, b2, h2, 256, 128);
    convT_kernel<3, 16, false><<<dim3(2, BB), blk, 0, stream>>>(h2, nullptr, w3, b3, h3, 128, 64);
    head_kernel<<<dim3(BB), blk, 0, stream>>>(h3, w4, b4, control, avg_shape, bf_out);
    locw_kernel<<<dim3(5, BB), blk, 0, stream>>>(control, loc_w);
    fbins_kernel<<<dim3((NBINS + 255) / 256), blk, 0, stream>>>(fbins);

    // pass 1: shape white noise in frequency domain
    pack_real<<<dim3((BB * NA + 255) / 256), blk, 0, stream>>>(wn, Abuf);
    run_fft(Abuf, Bbuf, -1.f, stream);
    mul_gains<<<dim3((NA + 255) / 256, BB), blk, 0, stream>>>(Abuf, avg_shape);
    run_fft(Abuf, Bbuf, +1.f, stream);

    // normalize + modulate
    std_kernel<<<dim3(BB), blk, 0, stream>>>(Abuf, scale);
    mod_kernel<<<dim3((NA + 255) / 256, BB), blk, 0, stream>>>(Abuf, control, f0, scale);

    // pass 2: turbulence filter
    run_fft(Abuf, Bbuf, -1.f, stream);
    mul_filter<<<dim3((NA + 255) / 256, BB), blk, 0, stream>>>(Abuf, fbins, loc_w);
    run_fft(Abuf, Bbuf, +1.f, stream);

    unpack_real<<<dim3((BB * NA + 255) / 256), blk, 0, stream>>>(Abuf, filtered);
}

// Round 3
// 758.656 us; speedup vs baseline: 2.2374x; 1.1702x over previous
//
#include <hip/hip_runtime.h>
#include <math.h>

#define BB 64
#define T_FR 200
#define NA 48000
#define N1F 240
#define N2F 200
#define NBINS 24001

__device__ inline float2 cmul(float2 a, float2 b)
{
    return make_float2(a.x * b.x - a.y * b.y, a.x * b.y + a.y * b.x);
}

// ---------------- in-LDS Stockham stage ----------------
// src/dst: flat LDS arrays, NC columns of length LEN with row stride STRIDE.
// Stage params (R, NN, SS) follow the verified global Stockham recurrence:
// reads src[q + SS*p + (LEN/R)*r], writes dst[q + SS*(R*p+rp)],
// twiddle e^{sign*2pi*i*(p*rp/NN + ((r*rp)%R)/R)}.
template<int R, int NN, int SS, int LEN, int STRIDE, int NC>
__device__ inline void lds_stage(const float2* __restrict__ src, float2* __restrict__ dst,
                                 float sign, int tid)
{
    constexpr int WORK = LEN / R;
    for (int idx = tid; idx < WORK * NC; idx += 256) {
        int col = idx / WORK;
        int t = idx - col * WORK;
        int p = t / SS, q = t - p * SS;
        const float2* sc = src + col * STRIDE;
        float2* dc = dst + col * STRIDE;
        float2 v[R];
#pragma unroll
        for (int r = 0; r < R; ++r) v[r] = sc[q + SS * p + WORK * r];
        float2 u[R];
#pragma unroll
        for (int m = 0; m < R; ++m) {
            float sn, cs;
            sincospif(sign * 2.f * (float)m / (float)R, &sn, &cs);
            u[m] = make_float2(cs, sn);
        }
        float sn0, cs0;
        sincospif(sign * 2.f * (float)p / (float)NN, &sn0, &cs0);
        float2 w0 = make_float2(cs0, sn0);
        float2 wc = make_float2(1.f, 0.f);
        int ob = q + SS * R * p;
#pragma unroll
        for (int rp = 0; rp < R; ++rp) {
            float re = 0.f, im = 0.f;
#pragma unroll
            for (int r = 0; r < R; ++r) {
                int m = (r * rp) % R;
                re += v[r].x * u[m].x - v[r].y * u[m].y;
                im += v[r].x * u[m].y + v[r].y * u[m].x;
            }
            dc[ob + SS * rp] = make_float2(re * wc.x - im * wc.y, re * wc.y + im * wc.x);
            wc = cmul(wc, w0);
        }
    }
}

// 240 = 8*6*5 ; result lands in B (A->B->A->B)
__device__ inline void fft240(float2* A, float2* B, float sign, int tid)
{
    lds_stage<8, 240, 1, 240, 241, 16>(A, B, sign, tid); __syncthreads();
    lds_stage<6, 30, 8, 240, 241, 16>(B, A, sign, tid); __syncthreads();
    lds_stage<5, 5, 48, 240, 241, 16>(A, B, sign, tid); __syncthreads();
}

// 200 = 8*5*5 ; result lands in B (A->B->A->B)
__device__ inline void fft200(float2* A, float2* B, float sign, int tid)
{
    lds_stage<8, 200, 1, 200, 201, 8>(A, B, sign, tid); __syncthreads();
    lds_stage<5, 25, 8, 200, 201, 8>(B, A, sign, tid); __syncthreads();
    lds_stage<5, 5, 40, 200, 201, 8>(A, B, sign, tid); __syncthreads();
}

// ---------------- pass A: wn -> I[b][k1][n2] = tw * FFT240_n1(x[200*n1+n2]) ----------------
__global__ __launch_bounds__(256) void passA_kernel(const float* __restrict__ wn,
                                                    float2* __restrict__ I)
{
    __shared__ float2 La[16 * 241], Lb[16 * 241];
    int b = blockIdx.y;
    int n20 = blockIdx.x * 16;
    int cc = min(16, 200 - n20);
    int tid = threadIdx.x;
    for (int idx = tid; idx < 240 * 16; idx += 256) {
        int n1 = idx >> 4, j = idx & 15;
        float v = 0.f;
        if (j < cc) v = wn[(size_t)b * NA + n1 * 200 + n20 + j];
        La[j * 241 + n1] = make_float2(v, 0.f);
    }
    __syncthreads();
    fft240(La, Lb, -1.f, tid);
    for (int idx = tid; idx < 240 * 16; idx += 256) {
        int k1 = idx >> 4, j = idx & 15;
        if (j >= cc) continue;
        int n2 = n20 + j;
        int a = (n2 * k1) % NA;
        float sn, cs;
        sincospif(-2.f * (float)a / (float)NA, &sn, &cs);
        I[(size_t)b * NA + k1 * 200 + n2] = cmul(Lb[j * 241 + k1], make_float2(cs, sn));
    }
}

// ---------------- pass B: per k1-row: FFT200 fwd -> spectral mul -> FFT200 inv -> tw ----------------
// MODE 0: gains (band lookup) + Parseval accumulation for std. MODE 1: turbulence filter.
template<int MODE>
__global__ __launch_bounds__(256) void passB_kernel(float2* __restrict__ I,
    const float* __restrict__ avg_shape, const float* __restrict__ fbins,
    const float* __restrict__ loc_w, float* __restrict__ acc, float* __restrict__ z0)
{
    __shared__ float2 La[8 * 201], Lb[8 * 201];
    __shared__ float gsh[32];
    __shared__ float red[256];
    int b = blockIdx.y;
    int row0 = blockIdx.x * 8;
    int tid = threadIdx.x;
    if (MODE == 0) { if (tid < 32) gsh[tid] = avg_shape[b * 32 + tid]; }
    else           { if (tid < 5)  gsh[tid] = loc_w[b * 5 + tid]; }
    for (int idx = tid; idx < 8 * 200; idx += 256) {
        int row = idx / 200, e = idx - row * 200;
        La[row * 201 + e] = I[(size_t)b * NA + (row0 + row) * 200 + e];
    }
    __syncthreads();
    fft200(La, Lb, -1.f, tid);
    float part = 0.f;
    for (int idx = tid; idx < 8 * 200; idx += 256) {
        int row = idx / 200, k2 = idx - row * 200;
        int k1 = row0 + row;
        int k = k1 + 240 * k2;
        int kbin = min(k, NA - k);
        float2 X = Lb[row * 201 + k2];
        if (MODE == 0) {
            int j = (kbin * 32) / NBINS;
            if (j < 31 && (NBINS * (j + 1)) / 32 <= kbin) ++j;
            float g = gsh[j];
            float2 Z = make_float2(X.x * g, X.y * g);
            part += Z.x * Z.x + Z.y * Z.y;
            if (k == 0) z0[b] = Z.x;
            Lb[row * 201 + k2] = make_float2(Z.x * (1.f / NA), Z.y * (1.f / NA));
        } else {
            float tf = 0.f;
#pragma unroll
            for (int c = 0; c < 5; ++c) tf += gsh[c] * fbins[c * NBINS + kbin];
            tf *= (1.f / NA);
            Lb[row * 201 + k2] = make_float2(X.x * tf, X.y * tf);
        }
    }
    if (MODE == 0) {
        red[tid] = part;
        __syncthreads();
        for (int st = 128; st > 0; st >>= 1) {
            if (tid < st) red[tid] += red[tid + st];
            __syncthreads();
        }
        if (tid == 0) atomicAdd(&acc[b], red[0]);
    }
    __syncthreads();
    fft200(Lb, La, +1.f, tid);
    for (int idx = tid; idx < 8 * 200; idx += 256) {
        int row = idx / 200, n2 = idx - row * 200;
        int k1 = row0 + row;
        int a = (n2 * k1) % NA;
        float sn, cs;
        sincospif(2.f * (float)a / (float)NA, &sn, &cs);
        I[(size_t)b * NA + k1 * 200 + n2] = cmul(La[row * 201 + n2], make_float2(cs, sn));
    }
}

// ---------------- pass C: inv FFT240 (shaped y) -> scale*mod -> fwd FFT240 + tw ----------------
__global__ __launch_bounds__(256) void passC_kernel(float2* __restrict__ I,
    const float* __restrict__ control, const float* __restrict__ f0,
    const float* __restrict__ scale)
{
    __shared__ float2 La[16 * 241], Lb[16 * 241];
    __shared__ float ctl3[600];
    __shared__ float f0s[200];
    int b = blockIdx.y;
    int n20 = blockIdx.x * 16;
    int cc = min(16, 200 - n20);
    int tid = threadIdx.x;
    for (int i = tid; i < 600; i += 256) ctl3[i] = control[(size_t)b * 1600 + i];
    for (int i = tid; i < 200; i += 256) f0s[i] = f0[b * 200 + i];
    for (int idx = tid; idx < 240 * 16; idx += 256) {
        int k1 = idx >> 4, j = idx & 15;
        float2 v = make_float2(0.f, 0.f);
        if (j < cc) v = I[(size_t)b * NA + k1 * 200 + n20 + j];
        La[j * 241 + k1] = v;
    }
    __syncthreads();
    fft240(La, Lb, +1.f, tid);   // Lb.x = shaped y at n = 200*n1 + n2
    float sc = scale[b];
    for (int idx = tid; idx < 240 * 16; idx += 256) {
        int n1 = idx >> 4, j = idx & 15;
        int n2 = n20 + j;
        int n = 200 * n1 + n2;
        float sf = ((float)n + 0.5f) * (1.f / 240.f) - 0.5f;
        sf = fminf(fmaxf(sf, 0.f), 199.f);
        int i0 = (int)sf;
        int i1 = min(i0 + 1, 199);
        float w = sf - (float)i0;
        float inh = ctl3[i0] * (1.f - w) + ctl3[i1] * w;
        float exh = ctl3[200 + i0] * (1.f - w) + ctl3[200 + i1] * w;
        float pr  = ctl3[400 + i0] * (1.f - w) + ctl3[400 + i1] * w;
        float v0 = f0s[i0] > 0.f ? 1.f : 0.f;
        float v1 = f0s[i1] > 0.f ? 1.f : 0.f;
        float vv = v0 * (1.f - w) + v1 * w;
        float m = inh * (1.f - vv) + exh * pr;
        float y = Lb[j * 241 + n1].x * sc;
        La[j * 241 + n1] = make_float2(y * m, 0.f);
    }
    __syncthreads();
    fft240(La, Lb, -1.f, tid);
    for (int idx = tid; idx < 240 * 16; idx += 256) {
        int k1 = idx >> 4, j = idx & 15;
        if (j >= cc) continue;
        int n2 = n20 + j;
        int a = (n2 * k1) % NA;
        float sn, cs;
        sincospif(-2.f * (float)a / (float)NA, &sn, &cs);
        I[(size_t)b * NA + k1 * 200 + n2] = cmul(Lb[j * 241 + k1], make_float2(cs, sn));
    }
}

// ---------------- pass D: inv FFT240 -> real audio out ----------------
__global__ __launch_bounds__(256) void passD_kernel(const float2* __restrict__ I,
                                                    float* __restrict__ out)
{
    __shared__ float2 La[16 * 241], Lb[16 * 241];
    int b = blockIdx.y;
    int n20 = blockIdx.x * 16;
    int cc = min(16, 200 - n20);
    int tid = threadIdx.x;
    for (int idx = tid; idx < 240 * 16; idx += 256) {
        int k1 = idx >> 4, j = idx & 15;
        float2 v = make_float2(0.f, 0.f);
        if (j < cc) v = I[(size_t)b * NA + k1 * 200 + n20 + j];
        La[j * 241 + k1] = v;
    }
    __syncthreads();
    fft240(La, Lb, +1.f, tid);
    for (int idx = tid; idx < 240 * 16; idx += 256) {
        int n1 = idx >> 4, j = idx & 15;
        if (j >= cc) continue;
        out[(size_t)b * NA + 200 * n1 + n20 + j] = Lb[j * 241 + n1].x;
    }
}

// ---------------- small setup kernels ----------------
__global__ void init_kernel(float* __restrict__ acc, float* __restrict__ z0)
{
    int i = threadIdx.x;
    if (i < 64) { acc[i] = 0.f; z0[i] = 0.f; }
}

__global__ void finalize_scale(const float* __restrict__ acc, const float* __restrict__ z0,
                               float* __restrict__ scale)
{
    int b = threadIdx.x;
    if (b < 64) {
        float var = (acc[b] - z0[b] * z0[b]) / (48000.f * 47999.f);
        scale[b] = 0.1f / sqrtf(var);
    }
}

// ---------------- tiled conv1d with time-tiling ----------------
// block: (og, tq, b). 32 out-ch x 56-t tile. thread: o_local=tid>>3, tc=tid&7 -> 7 t each.
template<int K, int CHUNK, bool VOICED>
__global__ __launch_bounds__(256) void convT_kernel(
    const float* __restrict__ in, const float* __restrict__ f0,
    const float* __restrict__ w, const float* __restrict__ bias,
    float* __restrict__ out, int Cin, int Cout)
{
    constexpr int HALO = K / 2;
    constexpr int TW = 56 + 2 * HALO;
    __shared__ float xs[CHUNK][TW + 1];
    __shared__ float wst[CHUNK * K * 32];
    const int og = blockIdx.x, tq = blockIdx.y, b = blockIdx.z;
    const int tid = threadIdx.x;
    const int o_local = tid >> 3;
    const int tc = tid & 7;
    const int tbase = tq * 56;
    const int t0 = tbase + tc * 7;
    const int o = og * 32 + o_local;
    const int Creal = VOICED ? (Cin - 1) : Cin;

    float acc[7];
#pragma unroll
    for (int j = 0; j < 7; ++j) acc[j] = 0.f;

    const int nch = (Cin + CHUNK - 1) / CHUNK;
    for (int ci = 0; ci < nch; ++ci) {
        const int c0 = ci * CHUNK;
        const int cc = min(CHUNK, Cin - c0);
        __syncthreads();
        for (int idx = tid; idx < cc * TW; idx += 256) {
            int ii = idx / TW;
            int tt = idx - ii * TW;
            int t = tbase - HALO + tt;
            int gi = c0 + ii;
            float v = 0.f;
            if (t >= 0 && t < 200) {
                if (VOICED && gi == Cin - 1)
                    v = (f0[b * 200 + t] > 0.f) ? 1.f : 0.f;
                else
                    v = in[((size_t)b * Creal + gi) * 200 + t];
            }
            xs[ii][tt] = v;
        }
        for (int idx = tid; idx < cc * K * 32; idx += 256) {
            int o2 = idx & 31;
            int rest = idx >> 5;
            int k = rest % K;
            int ii = rest / K;
            wst[(ii * K + k) * 32 + o2] =
                w[((size_t)(og * 32 + o2) * Cin + (c0 + ii)) * K + k];
        }
        __syncthreads();
        for (int ii = 0; ii < cc; ++ii) {
            float xr[7 + 2 * HALO];
#pragma unroll
            for (int j = 0; j < 7 + 2 * HALO; ++j) xr[j] = xs[ii][tc * 7 + j];
            float wr[K];
#pragma unroll
            for (int k = 0; k < K; ++k) wr[k] = wst[(ii * K + k) * 32 + o_local];
#pragma unroll
            for (int j = 0; j < 7; ++j) {
#pragma unroll
                for (int k = 0; k < K; ++k) acc[j] += xr[j + k] * wr[k];
            }
        }
    }
    const float bz = bias[o];
    float* ob = out + ((size_t)b * Cout + o) * 200;
#pragma unroll
    for (int j = 0; j < 7; ++j) {
        int t = t0 + j;
        if (t < 200) {
            float v = acc[j] + bz;
            ob[t] = (v >= 0.f) ? v : 0.1f * v;
        }
    }
}

// ---------------- head: conv4 (40x64 k1) + activations + avg_shape ----------------
__global__ void head_kernel(const float* __restrict__ h3, const float* __restrict__ w4,
                            const float* __restrict__ b4, float* __restrict__ control,
                            float* __restrict__ avg_shape, float* __restrict__ out_bf)
{
    __shared__ float w4s[40 * 64];
    __shared__ float b4s[40];
    __shared__ float sp[200 * 33];
    int b = blockIdx.x;
    for (int j = threadIdx.x; j < 40 * 64; j += 256) w4s[j] = w4[j];
    if (threadIdx.x < 40) b4s[threadIdx.x] = b4[threadIdx.x];
    __syncthreads();
    int t = threadIdx.x;
    if (t < 200) {
        float p[40];
#pragma unroll
        for (int o = 0; o < 40; ++o) p[o] = b4s[o];
        const float* hb = h3 + (size_t)b * 64 * 200;
        for (int i = 0; i < 64; ++i) {
            float h = hb[i * 200 + t];
#pragma unroll
            for (int o = 0; o < 40; ++o) p[o] += h * w4s[o * 64 + i];
        }
        float inh = 1.f / (1.f + expf(-p[0]));
        float exh = 1.f / (1.f + expf(-p[1]));
        float pr  = 1.f / (1.f + expf(-p[2]));
        float mx = p[3];
#pragma unroll
        for (int c = 1; c < 32; ++c) mx = fmaxf(mx, p[3 + c]);
        float e[32];
        float sum = 0.f;
#pragma unroll
        for (int c = 0; c < 32; ++c) { e[c] = expf(p[3 + c] - mx); sum += e[c]; }
        float inv = 1.f / sum;
#pragma unroll
        for (int c = 0; c < 32; ++c) sp[t * 33 + c] = e[c] * inv;
        float mx2 = p[35];
#pragma unroll
        for (int c = 1; c < 5; ++c) mx2 = fmaxf(mx2, p[35 + c]);
        float e2[5];
        float s2 = 0.f;
#pragma unroll
        for (int c = 0; c < 5; ++c) { e2[c] = expf(p[35 + c] - mx2); s2 += e2[c]; }
        float inv2 = 1.f / s2;
        float* ctl = control + (size_t)b * 8 * 200;
        ctl[0 * 200 + t] = inh;
        ctl[1 * 200 + t] = exh;
        ctl[2 * 200 + t] = pr;
#pragma unroll
        for (int c = 0; c < 5; ++c) ctl[(3 + c) * 200 + t] = e2[c] * inv2;
        float* bf = out_bf + (size_t)b * 3 * 200;
        bf[0 * 200 + t] = pr;
        bf[1 * 200 + t] = inh;
        bf[2 * 200 + t] = exh;
    }
    __syncthreads();
    if (t < 32) {
        float s = 0.f;
        for (int j = 0; j < 200; ++j) s += sp[j * 33 + t];
        avg_shape[b * 32 + t] = s * (1.f / 200.f);
    }
}

// ---------------- loc_w[b,c] = mean over audio of interp(turb[b,c]) ----------------
__global__ void locw_kernel(const float* __restrict__ control, float* __restrict__ loc_w)
{
    int c = blockIdx.x, b = blockIdx.y;
    const float* src = control + ((size_t)b * 8 + 3 + c) * 200;
    float s = 0.f;
    for (int i = threadIdx.x; i < NA; i += 256) {
        float sf = (i + 0.5f) * (200.0f / 48000.0f) - 0.5f;
        sf = fminf(fmaxf(sf, 0.f), 199.f);
        int i0 = (int)sf;
        int i1 = min(i0 + 1, 199);
        float w = sf - (float)i0;
        s += src[i0] * (1.f - w) + src[i1] * w;
    }
    __shared__ float red[256];
    red[threadIdx.x] = s;
    __syncthreads();
    for (int st = 128; st > 0; st >>= 1) {
        if (threadIdx.x < st) red[threadIdx.x] += red[threadIdx.x + st];
        __syncthreads();
    }
    if (threadIdx.x == 0) loc_w[b * 5 + c] = red[0] * (1.f / 48000.f);
}

// ---------------- fbins ----------------
__device__ inline float filter_shape_val(int c, int i)
{
    float lin = (float)i * (1.f / 31.f);
    if (c == 0) { float z = (lin - 0.2f) * 10.f;          return expf(-0.5f * z * z); }
    if (c == 1) { float z = (lin - 0.1f) * 10.f;          return expf(-0.5f * z * z); }
    if (c == 2) { float z = (lin - 0.4f) * (1.f / 0.15f); return expf(-0.5f * z * z); }
    if (c == 3) { float z = (lin - 0.6f) * 10.f;          return expf(-0.5f * z * z); }
    float v = 0.1f + 0.9f * lin;
    return v * v;
}

__global__ void fbins_kernel(float* __restrict__ fbins)
{
    int k = blockIdx.x * 256 + threadIdx.x;
    if (k >= NBINS) return;
    float sf = (k + 0.5f) * (32.0f / 24001.0f) - 0.5f;
    sf = fminf(fmaxf(sf, 0.f), 31.f);
    int i0 = (int)sf;
    int i1 = min(i0 + 1, 31);
    float w = sf - (float)i0;
#pragma unroll
    for (int c = 0; c < 5; ++c)
        fbins[c * NBINS + k] = filter_shape_val(c, i0) * (1.f - w) + filter_shape_val(c, i1) * w;
}

extern "C" void kernel_launch(void* const* d_in, const int* in_sizes, int n_in,
                              void* d_out, int out_size, void* d_ws, size_t ws_size,
                              hipStream_t stream)
{
    const float* cond = (const float*)d_in[0];
    const float* f0   = (const float*)d_in[1];
    const float* wn   = (const float*)d_in[2];
    const float* w1   = (const float*)d_in[3];
    const float* b1   = (const float*)d_in[4];
    const float* w2   = (const float*)d_in[5];
    const float* b2   = (const float*)d_in[6];
    const float* w3   = (const float*)d_in[7];
    const float* b3   = (const float*)d_in[8];
    const float* w4   = (const float*)d_in[9];
    const float* b4   = (const float*)d_in[10];

    float* out = (float*)d_out;
    float* filtered = out;
    float* bf_out   = out + (size_t)BB * NA;

    char* ws = (char*)d_ws;
    float2* I = (float2*)ws;                                   // 24,576,000 B
    float* h1 = (float*)(ws + 24576000);                       // 13,107,200 B
    float* h2 = (float*)(ws + 24576000 + 13107200);            //  6,553,600 B
    float* h3 = (float*)(ws + 24576000 + 13107200 + 6553600);  //  3,276,800 B
    float* tail      = (float*)(ws + 24576000 + 13107200 + 6553600 + 3276800);
    float* control   = tail;                  // 102,400
    float* avg_shape = control + 102400;      // 2,048
    float* loc_w     = avg_shape + 2048;      // 320
    float* acc       = loc_w + 320;           // 64
    float* z0        = acc + 64;              // 64
    float* scale     = z0 + 64;               // 64
    float* fbins     = scale + 64;            // 120,005

    dim3 blk(256);

    init_kernel<<<1, 64, 0, stream>>>(acc, z0);

    // conv stack (tiled, time-split for occupancy)
    convT_kernel<5, 16, true ><<<dim3(8, 4, BB), blk, 0, stream>>>(cond, f0, w1, b1, h1, 129, 256);
    convT_kernel<3, 16, false><<<dim3(4, 4, BB), blk, 0, stream>>>(h1, nullptr, w2, b2, h2, 256, 128);
    convT_kernel<3, 16, false><<<dim3(2, 4, BB), blk, 0, stream>>>(h2, nullptr, w3, b3, h3, 128, 64);
    head_kernel<<<dim3(BB), blk, 0, stream>>>(h3, w4, b4, control, avg_shape, bf_out);
    locw_kernel<<<dim3(5, BB), blk, 0, stream>>>(control, loc_w);
    fbins_kernel<<<dim3((NBINS + 255) / 256), blk, 0, stream>>>(fbins);

    // fused four-step FFT pipeline (N = 240 x 200)
    passA_kernel<<<dim3(13, BB), blk, 0, stream>>>(wn, I);
    passB_kernel<0><<<dim3(30, BB), blk, 0, stream>>>(I, avg_shape, fbins, loc_w, acc, z0);
    finalize_scale<<<1, 64, 0, stream>>>(acc, z0, scale);
    passC_kernel<<<dim3(13, BB), blk, 0, stream>>>(I, control, f0, scale);
    passB_kernel<1><<<dim3(30, BB), blk, 0, stream>>>(I, avg_shape, fbins, loc_w, acc, z0);
    passD_kernel<<<dim3(13, BB), blk, 0, stream>>>(I, filtered);
}

// Round 4
// 664.008 us; speedup vs baseline: 2.5563x; 1.1425x over previous
//
#include <hip/hip_runtime.h>
#include <math.h>

#define BB 64
#define T_FR 200
#define NA 48000
#define NBINS 24001

__device__ inline float2 cmul(float2 a, float2 b)
{
    return make_float2(a.x * b.x - a.y * b.y, a.x * b.y + a.y * b.x);
}

// ---------------- compile-time unit roots (fold to adds for 0/±1 entries) ----------------
template<int R> __device__ __forceinline__ void fill_roots(float (&cr)[R], float (&si)[R]);
template<> __device__ __forceinline__ void fill_roots<8>(float (&cr)[8], float (&si)[8])
{
    const float C = 0.70710678118654752f;
    cr[0]=1.f; cr[1]=C;  cr[2]=0.f;  cr[3]=-C; cr[4]=-1.f; cr[5]=-C;  cr[6]=0.f;  cr[7]=C;
    si[0]=0.f; si[1]=C;  si[2]=1.f;  si[3]=C;  si[4]=0.f;  si[5]=-C;  si[6]=-1.f; si[7]=-C;
}
template<> __device__ __forceinline__ void fill_roots<6>(float (&cr)[6], float (&si)[6])
{
    const float S = 0.86602540378443865f;
    cr[0]=1.f; cr[1]=0.5f; cr[2]=-0.5f; cr[3]=-1.f; cr[4]=-0.5f; cr[5]=0.5f;
    si[0]=0.f; si[1]=S;    si[2]=S;     si[3]=0.f;  si[4]=-S;    si[5]=-S;
}
template<> __device__ __forceinline__ void fill_roots<5>(float (&cr)[5], float (&si)[5])
{
    cr[0]=1.f; cr[1]=0.30901699437494742f; cr[2]=-0.80901699437494742f;
    cr[3]=-0.80901699437494742f; cr[4]=0.30901699437494742f;
    si[0]=0.f; si[1]=0.95105651629515357f; si[2]=0.58778525229247313f;
    si[3]=-0.58778525229247313f; si[4]=-0.95105651629515357f;
}

// ---------------- in-LDS Stockham stage ----------------
// reads src[q + SS*p + (LEN/R)*r], writes dst[q + SS*(R*p+rp)],
// twiddle e^{SIGNI*2pi*i*(p*rp/NN + ((r*rp)%R)/R)}.  NN==R => p==0 (no sincos).
template<int SIGNI, int R, int NN, int SS, int LEN, int STRIDE, int NC>
__device__ __forceinline__ void lds_stage(const float2* __restrict__ src,
                                          float2* __restrict__ dst, int tid)
{
    constexpr int WORK = LEN / R;
    float cr[R], si[R];
    fill_roots<R>(cr, si);
    for (int idx = tid; idx < WORK * NC; idx += 256) {
        int col = idx / WORK;
        int t = idx - col * WORK;
        int p = t / SS, q = t - p * SS;
        const float2* sc = src + col * STRIDE;
        float2* dc = dst + col * STRIDE;
        float2 v[R];
#pragma unroll
        for (int r = 0; r < R; ++r) v[r] = sc[q + SS * p + WORK * r];
        float2 w0 = make_float2(1.f, 0.f);
        if (NN != R) {
            float sn, cs;
            sincospif((float)(2 * SIGNI) * (float)p / (float)NN, &sn, &cs);
            w0 = make_float2(cs, sn);
        }
        float2 wc = make_float2(1.f, 0.f);
        int ob = q + SS * R * p;
#pragma unroll
        for (int rp = 0; rp < R; ++rp) {
            float re = 0.f, im = 0.f;
#pragma unroll
            for (int r = 0; r < R; ++r) {
                int m = (r * rp) % R;
                float ure = cr[m];
                float uim = (SIGNI > 0) ? si[m] : -si[m];
                re += v[r].x * ure - v[r].y * uim;
                im += v[r].x * uim + v[r].y * ure;
            }
            dc[ob + SS * rp] = make_float2(re * wc.x - im * wc.y, re * wc.y + im * wc.x);
            if (NN != R) wc = cmul(wc, w0);
        }
    }
}

// 240 = 8*6*5 ; result lands in B
template<int SIGNI>
__device__ __forceinline__ void fft240(float2* A, float2* B, int tid)
{
    lds_stage<SIGNI, 8, 240, 1, 240, 241, 16>(A, B, tid); __syncthreads();
    lds_stage<SIGNI, 6, 30, 8, 240, 241, 16>(B, A, tid); __syncthreads();
    lds_stage<SIGNI, 5, 5, 48, 240, 241, 16>(A, B, tid); __syncthreads();
}

// 200 = 8*5*5 ; result lands in B
template<int SIGNI>
__device__ __forceinline__ void fft200(float2* A, float2* B, int tid)
{
    lds_stage<SIGNI, 8, 200, 1, 200, 201, 8>(A, B, tid); __syncthreads();
    lds_stage<SIGNI, 5, 25, 8, 200, 201, 8>(B, A, tid); __syncthreads();
    lds_stage<SIGNI, 5, 5, 40, 200, 201, 8>(A, B, tid); __syncthreads();
}

// ---------------- pass A: wn -> I[b][k1][n2] = tw * FFT240_n1(x[200*n1+n2]) ----------------
__global__ __launch_bounds__(256) void passA_kernel(const float* __restrict__ wn,
                                                    float2* __restrict__ I)
{
    __shared__ float2 La[16 * 241], Lb[16 * 241];
    int b = blockIdx.y;
    int n20 = blockIdx.x * 16;
    int cc = min(16, 200 - n20);
    int tid = threadIdx.x;
    for (int idx = tid; idx < 240 * 16; idx += 256) {
        int n1 = idx >> 4, j = idx & 15;
        float v = 0.f;
        if (j < cc) v = wn[(size_t)b * NA + n1 * 200 + n20 + j];
        La[j * 241 + n1] = make_float2(v, 0.f);
    }
    __syncthreads();
    fft240<-1>(La, Lb, tid);
    for (int idx = tid; idx < 240 * 16; idx += 256) {
        int k1 = idx >> 4, j = idx & 15;
        if (j >= cc) continue;
        int n2 = n20 + j;
        int a = (n2 * k1) % NA;
        float sn, cs;
        sincospif(-2.f * (float)a / (float)NA, &sn, &cs);
        I[(size_t)b * NA + k1 * 200 + n2] = cmul(Lb[j * 241 + k1], make_float2(cs, sn));
    }
}

// ---------------- pass B: per k1-row: FFT200 fwd -> spectral mul -> FFT200 inv -> tw ----------------
template<int MODE>
__global__ __launch_bounds__(256) void passB_kernel(float2* __restrict__ I,
    const float* __restrict__ avg_shape, const float* __restrict__ fbins,
    const float* __restrict__ loc_w, float* __restrict__ acc, float* __restrict__ z0)
{
    __shared__ float2 La[8 * 201], Lb[8 * 201];
    __shared__ float gsh[32];
    __shared__ float red[256];
    int b = blockIdx.y;
    int row0 = blockIdx.x * 8;
    int tid = threadIdx.x;
    if (MODE == 0) { if (tid < 32) gsh[tid] = avg_shape[b * 32 + tid]; }
    else           { if (tid < 5)  gsh[tid] = loc_w[b * 5 + tid]; }
    for (int idx = tid; idx < 8 * 200; idx += 256) {
        int row = idx / 200, e = idx - row * 200;
        La[row * 201 + e] = I[(size_t)b * NA + (row0 + row) * 200 + e];
    }
    __syncthreads();
    fft200<-1>(La, Lb, tid);
    float part = 0.f;
    for (int idx = tid; idx < 8 * 200; idx += 256) {
        int row = idx / 200, k2 = idx - row * 200;
        int k1 = row0 + row;
        int k = k1 + 240 * k2;
        int kbin = min(k, NA - k);
        float2 X = Lb[row * 201 + k2];
        if (MODE == 0) {
            int j = (kbin * 32) / NBINS;
            if (j < 31 && (NBINS * (j + 1)) / 32 <= kbin) ++j;
            float g = gsh[j];
            float2 Z = make_float2(X.x * g, X.y * g);
            part += Z.x * Z.x + Z.y * Z.y;
            if (k == 0) z0[b] = Z.x;
            Lb[row * 201 + k2] = make_float2(Z.x * (1.f / NA), Z.y * (1.f / NA));
        } else {
            float tf = 0.f;
#pragma unroll
            for (int c = 0; c < 5; ++c) tf += gsh[c] * fbins[c * NBINS + kbin];
            tf *= (1.f / NA);
            Lb[row * 201 + k2] = make_float2(X.x * tf, X.y * tf);
        }
    }
    if (MODE == 0) {
        red[tid] = part;
        __syncthreads();
        for (int st = 128; st > 0; st >>= 1) {
            if (tid < st) red[tid] += red[tid + st];
            __syncthreads();
        }
        if (tid == 0) atomicAdd(&acc[b], red[0]);
    }
    __syncthreads();
    fft200<+1>(Lb, La, tid);
    for (int idx = tid; idx < 8 * 200; idx += 256) {
        int row = idx / 200, n2 = idx - row * 200;
        int k1 = row0 + row;
        int a = (n2 * k1) % NA;
        float sn, cs;
        sincospif(2.f * (float)a / (float)NA, &sn, &cs);
        I[(size_t)b * NA + k1 * 200 + n2] = cmul(La[row * 201 + n2], make_float2(cs, sn));
    }
}

// ---------------- pass C: inv FFT240 (shaped y) -> scale*mod -> fwd FFT240 + tw ----------------
__global__ __launch_bounds__(256) void passC_kernel(float2* __restrict__ I,
    const float* __restrict__ control, const float* __restrict__ f0,
    const float* __restrict__ scale)
{
    __shared__ float2 La[16 * 241], Lb[16 * 241];
    __shared__ float ctl3[600];
    __shared__ float f0s[200];
    int b = blockIdx.y;
    int n20 = blockIdx.x * 16;
    int cc = min(16, 200 - n20);
    int tid = threadIdx.x;
    for (int i = tid; i < 600; i += 256) ctl3[i] = control[(size_t)b * 1600 + i];
    for (int i = tid; i < 200; i += 256) f0s[i] = f0[b * 200 + i];
    for (int idx = tid; idx < 240 * 16; idx += 256) {
        int k1 = idx >> 4, j = idx & 15;
        float2 v = make_float2(0.f, 0.f);
        if (j < cc) v = I[(size_t)b * NA + k1 * 200 + n20 + j];
        La[j * 241 + k1] = v;
    }
    __syncthreads();
    fft240<+1>(La, Lb, tid);   // Lb.x = shaped y at n = 200*n1 + n2
    float sc = scale[b];
    for (int idx = tid; idx < 240 * 16; idx += 256) {
        int n1 = idx >> 4, j = idx & 15;
        int n2 = n20 + j;
        int n = 200 * n1 + n2;
        float sf = ((float)n + 0.5f) * (1.f / 240.f) - 0.5f;
        sf = fminf(fmaxf(sf, 0.f), 199.f);
        int i0 = (int)sf;
        int i1 = min(i0 + 1, 199);
        float w = sf - (float)i0;
        float inh = ctl3[i0] * (1.f - w) + ctl3[i1] * w;
        float exh = ctl3[200 + i0] * (1.f - w) + ctl3[200 + i1] * w;
        float pr  = ctl3[400 + i0] * (1.f - w) + ctl3[400 + i1] * w;
        float v0 = f0s[i0] > 0.f ? 1.f : 0.f;
        float v1 = f0s[i1] > 0.f ? 1.f : 0.f;
        float vv = v0 * (1.f - w) + v1 * w;
        float m = inh * (1.f - vv) + exh * pr;
        float y = Lb[j * 241 + n1].x * sc;
        La[j * 241 + n1] = make_float2(y * m, 0.f);
    }
    __syncthreads();
    fft240<-1>(La, Lb, tid);
    for (int idx = tid; idx < 240 * 16; idx += 256) {
        int k1 = idx >> 4, j = idx & 15;
        if (j >= cc) continue;
        int n2 = n20 + j;
        int a = (n2 * k1) % NA;
        float sn, cs;
        sincospif(-2.f * (float)a / (float)NA, &sn, &cs);
        I[(size_t)b * NA + k1 * 200 + n2] = cmul(Lb[j * 241 + k1], make_float2(cs, sn));
    }
}

// ---------------- pass D: inv FFT240 -> real audio out ----------------
__global__ __launch_bounds__(256) void passD_kernel(const float2* __restrict__ I,
                                                    float* __restrict__ out)
{
    __shared__ float2 La[16 * 241], Lb[16 * 241];
    int b = blockIdx.y;
    int n20 = blockIdx.x * 16;
    int cc = min(16, 200 - n20);
    int tid = threadIdx.x;
    for (int idx = tid; idx < 240 * 16; idx += 256) {
        int k1 = idx >> 4, j = idx & 15;
        float2 v = make_float2(0.f, 0.f);
        if (j < cc) v = I[(size_t)b * NA + k1 * 200 + n20 + j];
        La[j * 241 + k1] = v;
    }
    __syncthreads();
    fft240<+1>(La, Lb, tid);
    for (int idx = tid; idx < 240 * 16; idx += 256) {
        int n1 = idx >> 4, j = idx & 15;
        if (j >= cc) continue;
        out[(size_t)b * NA + 200 * n1 + n20 + j] = Lb[j * 241 + n1].x;
    }
}

// ---------------- small setup kernels ----------------
__global__ void init_kernel(float* __restrict__ acc, float* __restrict__ z0)
{
    int i = threadIdx.x;
    if (i < 64) { acc[i] = 0.f; z0[i] = 0.f; }
}

__global__ void finalize_scale(const float* __restrict__ acc, const float* __restrict__ z0,
                               float* __restrict__ scale)
{
    int b = threadIdx.x;
    if (b < 64) {
        float var = (acc[b] - z0[b] * z0[b]) / (48000.f * 47999.f);
        scale[b] = 0.1f / sqrtf(var);
    }
}

// ---------------- conv1d, LDS-lean: 64 out-ch x 64-t tile, 2ch x 8t per thread ----------------
// threads: o_local = tid>>3 (0..31) -> channels o_local, o_local+32 ; tc = tid&7 -> t0 = tc*8.
// xs rows and weight rows 16B-aligned; window read as 3x ds_read_b128,
// weights padded to 8 floats/row read as b128 (+b32 for K=5).
template<int K, bool VOICED>
__global__ __launch_bounds__(256) void convT2_kernel(
    const float* __restrict__ in, const float* __restrict__ f0,
    const float* __restrict__ w, const float* __restrict__ bias,
    float* __restrict__ out, int Cin, int Cout)
{
    constexpr int HALO = K / 2;
    constexpr int CHUNK = 16;
    constexpr int XW = 68;                 // >= 64 + 2*HALO, row = 272B (16B-aligned)
    __shared__ __align__(16) float xs[CHUNK][XW];
    __shared__ __align__(16) float wstp[CHUNK][64][8];
    const int og = blockIdx.x, tq = blockIdx.y, b = blockIdx.z;
    const int tid = threadIdx.x;
    const int o_local = tid >> 3;
    const int tc = tid & 7;
    const int tbase = tq * 64;
    const int o0 = og * 64 + o_local;
    const int o1 = o0 + 32;
    const int Creal = VOICED ? (Cin - 1) : Cin;

    float acc0[8], acc1[8];
#pragma unroll
    for (int j = 0; j < 8; ++j) { acc0[j] = 0.f; acc1[j] = 0.f; }

    const int nch = (Cin + CHUNK - 1) / CHUNK;
    for (int ci = 0; ci < nch; ++ci) {
        const int c0 = ci * CHUNK;
        const int cc = min(CHUNK, Cin - c0);
        __syncthreads();
        // stage input slab (coalesced)
        for (int idx = tid; idx < cc * XW; idx += 256) {
            int ii = idx / XW;
            int tt = idx - ii * XW;
            int t = tbase - HALO + tt;
            int gi = c0 + ii;
            float v = 0.f;
            if (t >= 0 && t < 200) {
                if (VOICED && gi == Cin - 1)
                    v = (f0[b * 200 + t] > 0.f) ? 1.f : 0.f;
                else
                    v = in[((size_t)b * Creal + gi) * 200 + t];
            }
            xs[ii][tt] = v;
        }
        // stage weights: wstp[ii][o2][k]  (source reads coalesced)
        for (int idx = tid; idx < cc * 64 * K; idx += 256) {
            int ii = idx / (64 * K);
            int rem = idx - ii * (64 * K);
            int o2 = rem / K;
            int k = rem - o2 * K;
            wstp[ii][o2][k] = w[((size_t)(og * 64 + o2) * Cin + (c0 + ii)) * K + k];
        }
        __syncthreads();
        for (int ii = 0; ii < cc; ++ii) {
            float4 r0 = *(const float4*)&xs[ii][tc * 8];
            float4 r1 = *(const float4*)&xs[ii][tc * 8 + 4];
            float4 r2 = *(const float4*)&xs[ii][tc * 8 + 8];
            float xw[12] = { r0.x, r0.y, r0.z, r0.w,
                             r1.x, r1.y, r1.z, r1.w,
                             r2.x, r2.y, r2.z, r2.w };
            float wr0[K], wr1[K];
            {
                float4 a = *(const float4*)&wstp[ii][o_local][0];
                wr0[0] = a.x; wr0[1] = a.y; wr0[2] = a.z;
                if (K > 3) { wr0[3] = a.w; wr0[4] = wstp[ii][o_local][4]; }
                float4 c = *(const float4*)&wstp[ii][o_local + 32][0];
                wr1[0] = c.x; wr1[1] = c.y; wr1[2] = c.z;
                if (K > 3) { wr1[3] = c.w; wr1[4] = wstp[ii][o_local + 32][4]; }
            }
#pragma unroll
            for (int j = 0; j < 8; ++j) {
#pragma unroll
                for (int k = 0; k < K; ++k) {
                    float xv = xw[j + k];
                    acc0[j] += xv * wr0[k];
                    acc1[j] += xv * wr1[k];
                }
            }
        }
    }
    const float bz0 = bias[o0];
    const float bz1 = bias[o1];
    const int ts = tbase + tc * 8;
    float* ob0 = out + ((size_t)b * Cout + o0) * 200;
    float* ob1 = out + ((size_t)b * Cout + o1) * 200;
    if (ts + 8 <= 200) {
        float v0[8], v1[8];
#pragma unroll
        for (int j = 0; j < 8; ++j) {
            float a = acc0[j] + bz0;
            float c = acc1[j] + bz1;
            v0[j] = (a >= 0.f) ? a : 0.1f * a;
            v1[j] = (c >= 0.f) ? c : 0.1f * c;
        }
        *(float4*)&ob0[ts]     = make_float4(v0[0], v0[1], v0[2], v0[3]);
        *(float4*)&ob0[ts + 4] = make_float4(v0[4], v0[5], v0[6], v0[7]);
        *(float4*)&ob1[ts]     = make_float4(v1[0], v1[1], v1[2], v1[3]);
        *(float4*)&ob1[ts + 4] = make_float4(v1[4], v1[5], v1[6], v1[7]);
    } else {
#pragma unroll
        for (int j = 0; j < 8; ++j) {
            int t = ts + j;
            if (t < 200) {
                float a = acc0[j] + bz0;
                float c = acc1[j] + bz1;
                ob0[t] = (a >= 0.f) ? a : 0.1f * a;
                ob1[t] = (c >= 0.f) ? c : 0.1f * c;
            }
        }
    }
}

// ---------------- head: conv4 (40x64 k1) + activations + avg_shape ----------------
__global__ void head_kernel(const float* __restrict__ h3, const float* __restrict__ w4,
                            const float* __restrict__ b4, float* __restrict__ control,
                            float* __restrict__ avg_shape, float* __restrict__ out_bf)
{
    __shared__ float w4s[40 * 64];
    __shared__ float b4s[40];
    __shared__ float sp[200 * 33];
    int b = blockIdx.x;
    for (int j = threadIdx.x; j < 40 * 64; j += 256) w4s[j] = w4[j];
    if (threadIdx.x < 40) b4s[threadIdx.x] = b4[threadIdx.x];
    __syncthreads();
    int t = threadIdx.x;
    if (t < 200) {
        float p[40];
#pragma unroll
        for (int o = 0; o < 40; ++o) p[o] = b4s[o];
        const float* hb = h3 + (size_t)b * 64 * 200;
        for (int i = 0; i < 64; ++i) {
            float h = hb[i * 200 + t];
#pragma unroll
            for (int o = 0; o < 40; ++o) p[o] += h * w4s[o * 64 + i];
        }
        float inh = 1.f / (1.f + expf(-p[0]));
        float exh = 1.f / (1.f + expf(-p[1]));
        float pr  = 1.f / (1.f + expf(-p[2]));
        float mx = p[3];
#pragma unroll
        for (int c = 1; c < 32; ++c) mx = fmaxf(mx, p[3 + c]);
        float e[32];
        float sum = 0.f;
#pragma unroll
        for (int c = 0; c < 32; ++c) { e[c] = expf(p[3 + c] - mx); sum += e[c]; }
        float inv = 1.f / sum;
#pragma unroll
        for (int c = 0; c < 32; ++c) sp[t * 33 + c] = e[c] * inv;
        float mx2 = p[35];
#pragma unroll
        for (int c = 1; c < 5; ++c) mx2 = fmaxf(mx2, p[35 + c]);
        float e2[5];
        float s2 = 0.f;
#pragma unroll
        for (int c = 0; c < 5; ++c) { e2[c] = expf(p[35 + c] - mx2); s2 += e2[c]; }
        float inv2 = 1.f / s2;
        float* ctl = control + (size_t)b * 8 * 200;
        ctl[0 * 200 + t] = inh;
        ctl[1 * 200 + t] = exh;
        ctl[2 * 200 + t] = pr;
#pragma unroll
        for (int c = 0; c < 5; ++c) ctl[(3 + c) * 200 + t] = e2[c] * inv2;
        float* bf = out_bf + (size_t)b * 3 * 200;
        bf[0 * 200 + t] = pr;
        bf[1 * 200 + t] = inh;
        bf[2 * 200 + t] = exh;
    }
    __syncthreads();
    if (t < 32) {
        float s = 0.f;
        for (int j = 0; j < 200; ++j) s += sp[j * 33 + t];
        avg_shape[b * 32 + t] = s * (1.f / 200.f);
    }
}

// ---------------- loc_w[b,c] = mean over audio of interp(turb[b,c]) ----------------
__global__ void locw_kernel(const float* __restrict__ control, float* __restrict__ loc_w)
{
    int c = blockIdx.x, b = blockIdx.y;
    const float* src = control + ((size_t)b * 8 + 3 + c) * 200;
    float s = 0.f;
    for (int i = threadIdx.x; i < NA; i += 256) {
        float sf = (i + 0.5f) * (200.0f / 48000.0f) - 0.5f;
        sf = fminf(fmaxf(sf, 0.f), 199.f);
        int i0 = (int)sf;
        int i1 = min(i0 + 1, 199);
        float w = sf - (float)i0;
        s += src[i0] * (1.f - w) + src[i1] * w;
    }
    __shared__ float red[256];
    red[threadIdx.x] = s;
    __syncthreads();
    for (int st = 128; st > 0; st >>= 1) {
        if (threadIdx.x < st) red[threadIdx.x] += red[threadIdx.x + st];
        __syncthreads();
    }
    if (threadIdx.x == 0) loc_w[b * 5 + c] = red[0] * (1.f / 48000.f);
}

// ---------------- fbins ----------------
__device__ inline float filter_shape_val(int c, int i)
{
    float lin = (float)i * (1.f / 31.f);
    if (c == 0) { float z = (lin - 0.2f) * 10.f;          return expf(-0.5f * z * z); }
    if (c == 1) { float z = (lin - 0.1f) * 10.f;          return expf(-0.5f * z * z); }
    if (c == 2) { float z = (lin - 0.4f) * (1.f / 0.15f); return expf(-0.5f * z * z); }
    if (c == 3) { float z = (lin - 0.6f) * 10.f;          return expf(-0.5f * z * z); }
    float v = 0.1f + 0.9f * lin;
    return v * v;
}

__global__ void fbins_kernel(float* __restrict__ fbins)
{
    int k = blockIdx.x * 256 + threadIdx.x;
    if (k >= NBINS) return;
    float sf = (k + 0.5f) * (32.0f / 24001.0f) - 0.5f;
    sf = fminf(fmaxf(sf, 0.f), 31.f);
    int i0 = (int)sf;
    int i1 = min(i0 + 1, 31);
    float w = sf - (float)i0;
#pragma unroll
    for (int c = 0; c < 5; ++c)
        fbins[c * NBINS + k] = filter_shape_val(c, i0) * (1.f - w) + filter_shape_val(c, i1) * w;
}

extern "C" void kernel_launch(void* const* d_in, const int* in_sizes, int n_in,
                              void* d_out, int out_size, void* d_ws, size_t ws_size,
                              hipStream_t stream)
{
    const float* cond = (const float*)d_in[0];
    const float* f0   = (const float*)d_in[1];
    const float* wn   = (const float*)d_in[2];
    const float* w1   = (const float*)d_in[3];
    const float* b1   = (const float*)d_in[4];
    const float* w2   = (const float*)d_in[5];
    const float* b2   = (const float*)d_in[6];
    const float* w3   = (const float*)d_in[7];
    const float* b3   = (const float*)d_in[8];
    const float* w4   = (const float*)d_in[9];
    const float* b4   = (const float*)d_in[10];

    float* out = (float*)d_out;
    float* filtered = out;
    float* bf_out   = out + (size_t)BB * NA;

    char* ws = (char*)d_ws;
    float2* I = (float2*)ws;                                   // 24,576,000 B
    float* h1 = (float*)(ws + 24576000);                       // 13,107,200 B
    float* h2 = (float*)(ws + 24576000 + 13107200);            //  6,553,600 B
    float* h3 = (float*)(ws + 24576000 + 13107200 + 6553600);  //  3,276,800 B
    float* tail      = (float*)(ws + 24576000 + 13107200 + 6553600 + 3276800);
    float* control   = tail;                  // 102,400
    float* avg_shape = control + 102400;      // 2,048
    float* loc_w     = avg_shape + 2048;      // 320
    float* acc       = loc_w + 320;           // 64
    float* z0        = acc + 64;              // 64
    float* scale     = z0 + 64;               // 64
    float* fbins     = scale + 64;            // 120,005

    dim3 blk(256);

    init_kernel<<<1, 64, 0, stream>>>(acc, z0);

    // conv stack (LDS-lean, 2ch x 8t per thread)
    convT2_kernel<5, true ><<<dim3(4, 4, BB), blk, 0, stream>>>(cond, f0, w1, b1, h1, 129, 256);
    convT2_kernel<3, false><<<dim3(2, 4, BB), blk, 0, stream>>>(h1, nullptr, w2, b2, h2, 256, 128);
    convT2_kernel<3, false><<<dim3(1, 4, BB), blk, 0, stream>>>(h2, nullptr, w3, b3, h3, 128, 64);
    head_kernel<<<dim3(BB), blk, 0, stream>>>(h3, w4, b4, control, avg_shape, bf_out);
    locw_kernel<<<dim3(5, BB), blk, 0, stream>>>(control, loc_w);
    fbins_kernel<<<dim3((NBINS + 255) / 256), blk, 0, stream>>>(fbins);

    // fused four-step FFT pipeline (N = 240 x 200)
    passA_kernel<<<dim3(13, BB), blk, 0, stream>>>(wn, I);
    passB_kernel<0><<<dim3(30, BB), blk, 0, stream>>>(I, avg_shape, fbins, loc_w, acc, z0);
    finalize_scale<<<1, 64, 0, stream>>>(acc, z0, scale);
    passC_kernel<<<dim3(13, BB), blk, 0, stream>>>(I, control, f0, scale);
    passB_kernel<1><<<dim3(30, BB), blk, 0, stream>>>(I, avg_shape, fbins, loc_w, acc, z0);
    passD_kernel<<<dim3(13, BB), blk, 0, stream>>>(I, filtered);
}

// Round 5
// 487.167 us; speedup vs baseline: 3.4843x; 1.3630x over previous
//
#include <hip/hip_runtime.h>
#include <math.h>

#define BB 64
#define T_FR 200
#define NA 48000
#define NBINS 24001

typedef __attribute__((ext_vector_type(4))) float f32x4;
typedef __attribute__((ext_vector_type(8))) short bf16x8;

__device__ __forceinline__ unsigned short f2bf(float x)
{
    unsigned u = __float_as_uint(x);
    u = (u + 0x7FFFu + ((u >> 16) & 1u)) >> 16;
    return (unsigned short)u;
}
__device__ __forceinline__ float bf2f(unsigned short h)
{
    return __uint_as_float(((unsigned)h) << 16);
}

__device__ inline float2 cmul(float2 a, float2 b)
{
    return make_float2(a.x * b.x - a.y * b.y, a.x * b.y + a.y * b.x);
}

// ================= MFMA conv =================
// xT:  [b][tRowsIn][CINP] bf16 (halo-offset rows, zero-padded)
// wT:  [kw][COUTP][CINP] bf16
// outT:[b][tRowsOut][COUTP] bf16, rows offset by tOffOut (next layer halo)
// Verified fragment layouts (learn_hip m89/m120):
//   A[m=lane&15][k=quad*8+j], B[k=quad*8+j][n=lane&15], D[row=quad*4+r][col=lane&15]
template<int NT, int TAPS, int CHUNKS, int CINP, int COUTP>
__global__ __launch_bounds__(256) void conv_mfma_kernel(
    const unsigned short* __restrict__ xT, int tRowsIn,
    const unsigned short* __restrict__ wT,
    const float* __restrict__ bias,
    unsigned short* __restrict__ outT, int tRowsOut, int tOffOut)
{
    const int b = blockIdx.y;
    const int t0 = blockIdx.x * 16;
    const int tid = threadIdx.x;
    const int wave = tid >> 6;
    const int lane = tid & 63;
    const int m = lane & 15;      // M (t) for A, N (o) for B, col for D
    const int quad = lane >> 4;   // 0..3
    const int n0 = wave * (NT * 16);

    f32x4 acc[NT];
#pragma unroll
    for (int nt = 0; nt < NT; ++nt) acc[nt] = (f32x4){0.f, 0.f, 0.f, 0.f};

    const unsigned short* xb = xT + (size_t)b * tRowsIn * CINP;
#pragma unroll
    for (int kw = 0; kw < TAPS; ++kw) {
        const unsigned short* wk = wT + (size_t)kw * COUTP * CINP;
        const unsigned short* xrow = xb + (size_t)(t0 + kw + m) * CINP + quad * 8;
#pragma unroll
        for (int ch = 0; ch < CHUNKS; ++ch) {
            const int k0 = ch * 32;
            bf16x8 a = *(const bf16x8*)(xrow + k0);
#pragma unroll
            for (int nt = 0; nt < NT; ++nt) {
                bf16x8 bfr = *(const bf16x8*)(wk + (size_t)(n0 + nt * 16 + m) * CINP + k0 + quad * 8);
                acc[nt] = __builtin_amdgcn_mfma_f32_16x16x32_bf16(a, bfr, acc[nt], 0, 0, 0);
            }
        }
    }
#pragma unroll
    for (int nt = 0; nt < NT; ++nt) {
        const int n = n0 + nt * 16 + m;
        const float bz = bias[n];
#pragma unroll
        for (int r = 0; r < 4; ++r) {
            const int t = t0 + quad * 4 + r;
            if (t < 200) {
                float v = acc[nt][r] + bz;
                v = (v >= 0.f) ? v : 0.1f * v;
                outT[((size_t)b * tRowsOut + t + tOffOut) * COUTP + n] = f2bf(v);
            }
        }
    }
}

// ---------------- prep: cond+voiced -> xpT1[b][212][160] bf16 ----------------
__global__ void prep_x1_kernel(const float* __restrict__ cond, const float* __restrict__ f0,
                               unsigned short* __restrict__ xpT1)
{
    int idx = blockIdx.x * 256 + threadIdx.x;
    const int total = BB * 212 * 160;
    if (idx >= total) return;
    int i = idx % 160;
    int rest = idx / 160;
    int tp = rest % 212;
    int b = rest / 212;
    int tt = tp - 2;
    float v = 0.f;
    if (tt >= 0 && tt < 200) {
        if (i < 128) v = cond[((size_t)b * 128 + i) * 200 + tt];
        else if (i == 128) v = (f0[b * 200 + tt] > 0.f) ? 1.f : 0.f;
    }
    xpT1[idx] = f2bf(v);
}

// ---------------- prep: weights -> wT[kw][COUTP][CINP] bf16 ----------------
template<int TAPS, int CINR, int CINP, int COUTP>
__global__ void prep_w_kernel(const float* __restrict__ w, unsigned short* __restrict__ wT)
{
    int idx = blockIdx.x * 256 + threadIdx.x;
    const int total = TAPS * COUTP * CINP;
    if (idx >= total) return;
    int i = idx % CINP;
    int rest = idx / CINP;
    int o = rest % COUTP;
    int kw = rest / COUTP;
    float v = (i < CINR) ? w[((size_t)o * CINR + i) * TAPS + kw] : 0.f;
    wT[idx] = f2bf(v);
}

// ---------------- zero fill (16B granules) ----------------
__global__ void zero16_kernel(uint4* __restrict__ p, int n16)
{
    int idx = blockIdx.x * 256 + threadIdx.x;
    if (idx < n16) p[idx] = make_uint4(0, 0, 0, 0);
}

// ================= FFT (unchanged from round 4) =================
template<int R> __device__ __forceinline__ void fill_roots(float (&cr)[R], float (&si)[R]);
template<> __device__ __forceinline__ void fill_roots<8>(float (&cr)[8], float (&si)[8])
{
    const float C = 0.70710678118654752f;
    cr[0]=1.f; cr[1]=C;  cr[2]=0.f;  cr[3]=-C; cr[4]=-1.f; cr[5]=-C;  cr[6]=0.f;  cr[7]=C;
    si[0]=0.f; si[1]=C;  si[2]=1.f;  si[3]=C;  si[4]=0.f;  si[5]=-C;  si[6]=-1.f; si[7]=-C;
}
template<> __device__ __forceinline__ void fill_roots<6>(float (&cr)[6], float (&si)[6])
{
    const float S = 0.86602540378443865f;
    cr[0]=1.f; cr[1]=0.5f; cr[2]=-0.5f; cr[3]=-1.f; cr[4]=-0.5f; cr[5]=0.5f;
    si[0]=0.f; si[1]=S;    si[2]=S;     si[3]=0.f;  si[4]=-S;    si[5]=-S;
}
template<> __device__ __forceinline__ void fill_roots<5>(float (&cr)[5], float (&si)[5])
{
    cr[0]=1.f; cr[1]=0.30901699437494742f; cr[2]=-0.80901699437494742f;
    cr[3]=-0.80901699437494742f; cr[4]=0.30901699437494742f;
    si[0]=0.f; si[1]=0.95105651629515357f; si[2]=0.58778525229247313f;
    si[3]=-0.58778525229247313f; si[4]=-0.95105651629515357f;
}

template<int SIGNI, int R, int NN, int SS, int LEN, int STRIDE, int NC>
__device__ __forceinline__ void lds_stage(const float2* __restrict__ src,
                                          float2* __restrict__ dst, int tid)
{
    constexpr int WORK = LEN / R;
    float cr[R], si[R];
    fill_roots<R>(cr, si);
    for (int idx = tid; idx < WORK * NC; idx += 256) {
        int col = idx / WORK;
        int t = idx - col * WORK;
        int p = t / SS, q = t - p * SS;
        const float2* sc = src + col * STRIDE;
        float2* dc = dst + col * STRIDE;
        float2 v[R];
#pragma unroll
        for (int r = 0; r < R; ++r) v[r] = sc[q + SS * p + WORK * r];
        float2 w0 = make_float2(1.f, 0.f);
        if (NN != R) {
            float sn, cs;
            sincospif((float)(2 * SIGNI) * (float)p / (float)NN, &sn, &cs);
            w0 = make_float2(cs, sn);
        }
        float2 wc = make_float2(1.f, 0.f);
        int ob = q + SS * R * p;
#pragma unroll
        for (int rp = 0; rp < R; ++rp) {
            float re = 0.f, im = 0.f;
#pragma unroll
            for (int r = 0; r < R; ++r) {
                int mm = (r * rp) % R;
                float ure = cr[mm];
                float uim = (SIGNI > 0) ? si[mm] : -si[mm];
                re += v[r].x * ure - v[r].y * uim;
                im += v[r].x * uim + v[r].y * ure;
            }
            dc[ob + SS * rp] = make_float2(re * wc.x - im * wc.y, re * wc.y + im * wc.x);
            if (NN != R) wc = cmul(wc, w0);
        }
    }
}

template<int SIGNI>
__device__ __forceinline__ void fft240(float2* A, float2* B, int tid)
{
    lds_stage<SIGNI, 8, 240, 1, 240, 241, 16>(A, B, tid); __syncthreads();
    lds_stage<SIGNI, 6, 30, 8, 240, 241, 16>(B, A, tid); __syncthreads();
    lds_stage<SIGNI, 5, 5, 48, 240, 241, 16>(A, B, tid); __syncthreads();
}

template<int SIGNI>
__device__ __forceinline__ void fft200(float2* A, float2* B, int tid)
{
    lds_stage<SIGNI, 8, 200, 1, 200, 201, 8>(A, B, tid); __syncthreads();
    lds_stage<SIGNI, 5, 25, 8, 200, 201, 8>(B, A, tid); __syncthreads();
    lds_stage<SIGNI, 5, 5, 40, 200, 201, 8>(A, B, tid); __syncthreads();
}

__global__ __launch_bounds__(256) void passA_kernel(const float* __restrict__ wn,
                                                    float2* __restrict__ I)
{
    __shared__ float2 La[16 * 241], Lb[16 * 241];
    int b = blockIdx.y;
    int n20 = blockIdx.x * 16;
    int cc = min(16, 200 - n20);
    int tid = threadIdx.x;
    for (int idx = tid; idx < 240 * 16; idx += 256) {
        int n1 = idx >> 4, j = idx & 15;
        float v = 0.f;
        if (j < cc) v = wn[(size_t)b * NA + n1 * 200 + n20 + j];
        La[j * 241 + n1] = make_float2(v, 0.f);
    }
    __syncthreads();
    fft240<-1>(La, Lb, tid);
    for (int idx = tid; idx < 240 * 16; idx += 256) {
        int k1 = idx >> 4, j = idx & 15;
        if (j >= cc) continue;
        int n2 = n20 + j;
        int a = (n2 * k1) % NA;
        float sn, cs;
        sincospif(-2.f * (float)a / (float)NA, &sn, &cs);
        I[(size_t)b * NA + k1 * 200 + n2] = cmul(Lb[j * 241 + k1], make_float2(cs, sn));
    }
}

template<int MODE>
__global__ __launch_bounds__(256) void passB_kernel(float2* __restrict__ I,
    const float* __restrict__ avg_shape, const float* __restrict__ fbins,
    const float* __restrict__ loc_w, float* __restrict__ acc, float* __restrict__ z0)
{
    __shared__ float2 La[8 * 201], Lb[8 * 201];
    __shared__ float gsh[32];
    __shared__ float red[256];
    int b = blockIdx.y;
    int row0 = blockIdx.x * 8;
    int tid = threadIdx.x;
    if (MODE == 0) { if (tid < 32) gsh[tid] = avg_shape[b * 32 + tid]; }
    else           { if (tid < 5)  gsh[tid] = loc_w[b * 5 + tid]; }
    for (int idx = tid; idx < 8 * 200; idx += 256) {
        int row = idx / 200, e = idx - row * 200;
        La[row * 201 + e] = I[(size_t)b * NA + (row0 + row) * 200 + e];
    }
    __syncthreads();
    fft200<-1>(La, Lb, tid);
    float part = 0.f;
    for (int idx = tid; idx < 8 * 200; idx += 256) {
        int row = idx / 200, k2 = idx - row * 200;
        int k1 = row0 + row;
        int k = k1 + 240 * k2;
        int kbin = min(k, NA - k);
        float2 X = Lb[row * 201 + k2];
        if (MODE == 0) {
            int j = (kbin * 32) / NBINS;
            if (j < 31 && (NBINS * (j + 1)) / 32 <= kbin) ++j;
            float g = gsh[j];
            float2 Z = make_float2(X.x * g, X.y * g);
            part += Z.x * Z.x + Z.y * Z.y;
            if (k == 0) z0[b] = Z.x;
            Lb[row * 201 + k2] = make_float2(Z.x * (1.f / NA), Z.y * (1.f / NA));
        } else {
            float tf = 0.f;
#pragma unroll
            for (int c = 0; c < 5; ++c) tf += gsh[c] * fbins[c * NBINS + kbin];
            tf *= (1.f / NA);
            Lb[row * 201 + k2] = make_float2(X.x * tf, X.y * tf);
        }
    }
    if (MODE == 0) {
        red[tid] = part;
        __syncthreads();
        for (int st = 128; st > 0; st >>= 1) {
            if (tid < st) red[tid] += red[tid + st];
            __syncthreads();
        }
        if (tid == 0) atomicAdd(&acc[b], red[0]);
    }
    __syncthreads();
    fft200<+1>(Lb, La, tid);
    for (int idx = tid; idx < 8 * 200; idx += 256) {
        int row = idx / 200, n2 = idx - row * 200;
        int k1 = row0 + row;
        int a = (n2 * k1) % NA;
        float sn, cs;
        sincospif(2.f * (float)a / (float)NA, &sn, &cs);
        I[(size_t)b * NA + k1 * 200 + n2] = cmul(La[row * 201 + n2], make_float2(cs, sn));
    }
}

__global__ __launch_bounds__(256) void passC_kernel(float2* __restrict__ I,
    const float* __restrict__ control, const float* __restrict__ f0,
    const float* __restrict__ scale)
{
    __shared__ float2 La[16 * 241], Lb[16 * 241];
    __shared__ float ctl3[600];
    __shared__ float f0s[200];
    int b = blockIdx.y;
    int n20 = blockIdx.x * 16;
    int cc = min(16, 200 - n20);
    int tid = threadIdx.x;
    for (int i = tid; i < 600; i += 256) ctl3[i] = control[(size_t)b * 1600 + i];
    for (int i = tid; i < 200; i += 256) f0s[i] = f0[b * 200 + i];
    for (int idx = tid; idx < 240 * 16; idx += 256) {
        int k1 = idx >> 4, j = idx & 15;
        float2 v = make_float2(0.f, 0.f);
        if (j < cc) v = I[(size_t)b * NA + k1 * 200 + n20 + j];
        La[j * 241 + k1] = v;
    }
    __syncthreads();
    fft240<+1>(La, Lb, tid);
    float sc = scale[b];
    for (int idx = tid; idx < 240 * 16; idx += 256) {
        int n1 = idx >> 4, j = idx & 15;
        int n2 = n20 + j;
        int n = 200 * n1 + n2;
        float sf = ((float)n + 0.5f) * (1.f / 240.f) - 0.5f;
        sf = fminf(fmaxf(sf, 0.f), 199.f);
        int i0 = (int)sf;
        int i1 = min(i0 + 1, 199);
        float w = sf - (float)i0;
        float inh = ctl3[i0] * (1.f - w) + ctl3[i1] * w;
        float exh = ctl3[200 + i0] * (1.f - w) + ctl3[200 + i1] * w;
        float pr  = ctl3[400 + i0] * (1.f - w) + ctl3[400 + i1] * w;
        float v0 = f0s[i0] > 0.f ? 1.f : 0.f;
        float v1 = f0s[i1] > 0.f ? 1.f : 0.f;
        float vv = v0 * (1.f - w) + v1 * w;
        float m = inh * (1.f - vv) + exh * pr;
        float y = Lb[j * 241 + n1].x * sc;
        La[j * 241 + n1] = make_float2(y * m, 0.f);
    }
    __syncthreads();
    fft240<-1>(La, Lb, tid);
    for (int idx = tid; idx < 240 * 16; idx += 256) {
        int k1 = idx >> 4, j = idx & 15;
        if (j >= cc) continue;
        int n2 = n20 + j;
        int a = (n2 * k1) % NA;
        float sn, cs;
        sincospif(-2.f * (float)a / (float)NA, &sn, &cs);
        I[(size_t)b * NA + k1 * 200 + n2] = cmul(Lb[j * 241 + k1], make_float2(cs, sn));
    }
}

__global__ __launch_bounds__(256) void passD_kernel(const float2* __restrict__ I,
                                                    float* __restrict__ out)
{
    __shared__ float2 La[16 * 241], Lb[16 * 241];
    int b = blockIdx.y;
    int n20 = blockIdx.x * 16;
    int cc = min(16, 200 - n20);
    int tid = threadIdx.x;
    for (int idx = tid; idx < 240 * 16; idx += 256) {
        int k1 = idx >> 4, j = idx & 15;
        float2 v = make_float2(0.f, 0.f);
        if (j < cc) v = I[(size_t)b * NA + k1 * 200 + n20 + j];
        La[j * 241 + k1] = v;
    }
    __syncthreads();
    fft240<+1>(La, Lb, tid);
    for (int idx = tid; idx < 240 * 16; idx += 256) {
        int n1 = idx >> 4, j = idx & 15;
        if (j >= cc) continue;
        out[(size_t)b * NA + 200 * n1 + n20 + j] = Lb[j * 241 + n1].x;
    }
}

__global__ void init_kernel(float* __restrict__ acc, float* __restrict__ z0)
{
    int i = threadIdx.x;
    if (i < 64) { acc[i] = 0.f; z0[i] = 0.f; }
}

__global__ void finalize_scale(const float* __restrict__ acc, const float* __restrict__ z0,
                               float* __restrict__ scale)
{
    int b = threadIdx.x;
    if (b < 64) {
        float var = (acc[b] - z0[b] * z0[b]) / (48000.f * 47999.f);
        scale[b] = 0.1f / sqrtf(var);
    }
}

// ---------------- head: conv4 (40x64 k1, bf16 h3) + activations + avg_shape ----------------
__global__ void head_kernel(const unsigned short* __restrict__ h3T, const float* __restrict__ w4,
                            const float* __restrict__ b4, float* __restrict__ control,
                            float* __restrict__ avg_shape, float* __restrict__ out_bf)
{
    __shared__ float w4s[40 * 64];
    __shared__ float b4s[40];
    __shared__ float sp[200 * 33];
    int b = blockIdx.x;
    for (int j = threadIdx.x; j < 40 * 64; j += 256) w4s[j] = w4[j];
    if (threadIdx.x < 40) b4s[threadIdx.x] = b4[threadIdx.x];
    __syncthreads();
    int t = threadIdx.x;
    if (t < 200) {
        float p[40];
#pragma unroll
        for (int o = 0; o < 40; ++o) p[o] = b4s[o];
        const unsigned short* hb = h3T + ((size_t)b * 200 + t) * 64;
        for (int i = 0; i < 64; ++i) {
            float h = bf2f(hb[i]);
#pragma unroll
            for (int o = 0; o < 40; ++o) p[o] += h * w4s[o * 64 + i];
        }
        float inh = 1.f / (1.f + expf(-p[0]));
        float exh = 1.f / (1.f + expf(-p[1]));
        float pr  = 1.f / (1.f + expf(-p[2]));
        float mx = p[3];
#pragma unroll
        for (int c = 1; c < 32; ++c) mx = fmaxf(mx, p[3 + c]);
        float e[32];
        float sum = 0.f;
#pragma unroll
        for (int c = 0; c < 32; ++c) { e[c] = expf(p[3 + c] - mx); sum += e[c]; }
        float inv = 1.f / sum;
#pragma unroll
        for (int c = 0; c < 32; ++c) sp[t * 33 + c] = e[c] * inv;
        float mx2 = p[35];
#pragma unroll
        for (int c = 1; c < 5; ++c) mx2 = fmaxf(mx2, p[35 + c]);
        float e2[5];
        float s2 = 0.f;
#pragma unroll
        for (int c = 0; c < 5; ++c) { e2[c] = expf(p[35 + c] - mx2); s2 += e2[c]; }
        float inv2 = 1.f / s2;
        float* ctl = control + (size_t)b * 8 * 200;
        ctl[0 * 200 + t] = inh;
        ctl[1 * 200 + t] = exh;
        ctl[2 * 200 + t] = pr;
#pragma unroll
        for (int c = 0; c < 5; ++c) ctl[(3 + c) * 200 + t] = e2[c] * inv2;
        float* bf = out_bf + (size_t)b * 3 * 200;
        bf[0 * 200 + t] = pr;
        bf[1 * 200 + t] = inh;
        bf[2 * 200 + t] = exh;
    }
    __syncthreads();
    if (t < 32) {
        float s = 0.f;
        for (int j = 0; j < 200; ++j) s += sp[j * 33 + t];
        avg_shape[b * 32 + t] = s * (1.f / 200.f);
    }
}

__global__ void locw_kernel(const float* __restrict__ control, float* __restrict__ loc_w)
{
    int c = blockIdx.x, b = blockIdx.y;
    const float* src = control + ((size_t)b * 8 + 3 + c) * 200;
    float s = 0.f;
    for (int i = threadIdx.x; i < NA; i += 256) {
        float sf = (i + 0.5f) * (200.0f / 48000.0f) - 0.5f;
        sf = fminf(fmaxf(sf, 0.f), 199.f);
        int i0 = (int)sf;
        int i1 = min(i0 + 1, 199);
        float w = sf - (float)i0;
        s += src[i0] * (1.f - w) + src[i1] * w;
    }
    __shared__ float red[256];
    red[threadIdx.x] = s;
    __syncthreads();
    for (int st = 128; st > 0; st >>= 1) {
        if (threadIdx.x < st) red[threadIdx.x] += red[threadIdx.x + st];
        __syncthreads();
    }
    if (threadIdx.x == 0) loc_w[b * 5 + c] = red[0] * (1.f / 48000.f);
}

__device__ inline float filter_shape_val(int c, int i)
{
    float lin = (float)i * (1.f / 31.f);
    if (c == 0) { float z = (lin - 0.2f) * 10.f;          return expf(-0.5f * z * z); }
    if (c == 1) { float z = (lin - 0.1f) * 10.f;          return expf(-0.5f * z * z); }
    if (c == 2) { float z = (lin - 0.4f) * (1.f / 0.15f); return expf(-0.5f * z * z); }
    if (c == 3) { float z = (lin - 0.6f) * 10.f;          return expf(-0.5f * z * z); }
    float v = 0.1f + 0.9f * lin;
    return v * v;
}

__global__ void fbins_kernel(float* __restrict__ fbins)
{
    int k = blockIdx.x * 256 + threadIdx.x;
    if (k >= NBINS) return;
    float sf = (k + 0.5f) * (32.0f / 24001.0f) - 0.5f;
    sf = fminf(fmaxf(sf, 0.f), 31.f);
    int i0 = (int)sf;
    int i1 = min(i0 + 1, 31);
    float w = sf - (float)i0;
#pragma unroll
    for (int c = 0; c < 5; ++c)
        fbins[c * NBINS + k] = filter_shape_val(c, i0) * (1.f - w) + filter_shape_val(c, i1) * w;
}

extern "C" void kernel_launch(void* const* d_in, const int* in_sizes, int n_in,
                              void* d_out, int out_size, void* d_ws, size_t ws_size,
                              hipStream_t stream)
{
    const float* cond = (const float*)d_in[0];
    const float* f0   = (const float*)d_in[1];
    const float* wn   = (const float*)d_in[2];
    const float* w1   = (const float*)d_in[3];
    const float* b1   = (const float*)d_in[4];
    const float* w2   = (const float*)d_in[5];
    const float* b2   = (const float*)d_in[6];
    const float* w3   = (const float*)d_in[7];
    const float* b3   = (const float*)d_in[8];
    const float* w4   = (const float*)d_in[9];
    const float* b4   = (const float*)d_in[10];

    float* out = (float*)d_out;
    float* filtered = out;
    float* bf_out   = out + (size_t)BB * NA;

    char* ws = (char*)d_ws;
    size_t off = 0;
    float2* I = (float2*)(ws + off);            off += 24576000;          // B*NA*8
    unsigned short* xpT1 = (unsigned short*)(ws + off); off += (size_t)BB * 212 * 160 * 2; // 4,341,760
    unsigned short* xpT2 = (unsigned short*)(ws + off); off += (size_t)BB * 210 * 256 * 2; // 6,881,280
    unsigned short* xpT3 = (unsigned short*)(ws + off); off += (size_t)BB * 210 * 128 * 2; // 3,440,640
    unsigned short* xpT4 = (unsigned short*)(ws + off); off += (size_t)BB * 200 * 64 * 2;  // 1,638,400
    unsigned short* wT1  = (unsigned short*)(ws + off); off += (size_t)5 * 256 * 160 * 2;  // 409,600
    unsigned short* wT2  = (unsigned short*)(ws + off); off += (size_t)3 * 128 * 256 * 2;  // 196,608
    unsigned short* wT3  = (unsigned short*)(ws + off); off += (size_t)3 * 64 * 128 * 2;   // 49,152
    float* control   = (float*)(ws + off);
    float* avg_shape = control + 102400;
    float* loc_w     = avg_shape + 2048;
    float* acc       = loc_w + 320;
    float* z0        = acc + 64;
    float* scale     = z0 + 64;
    float* fbins     = scale + 64;

    dim3 blk(256);

    init_kernel<<<1, 64, 0, stream>>>(acc, z0);

    // prep: bf16 transposed inputs + weights, zero-fill halo buffers
    {
        int n1 = BB * 212 * 160;
        prep_x1_kernel<<<dim3((n1 + 255) / 256), blk, 0, stream>>>(cond, f0, xpT1);
        int z2 = (BB * 210 * 256 * 2) / 16;
        zero16_kernel<<<dim3((z2 + 255) / 256), blk, 0, stream>>>((uint4*)xpT2, z2);
        int z3 = (BB * 210 * 128 * 2) / 16;
        zero16_kernel<<<dim3((z3 + 255) / 256), blk, 0, stream>>>((uint4*)xpT3, z3);
        prep_w_kernel<5, 129, 160, 256><<<dim3((5 * 256 * 160 + 255) / 256), blk, 0, stream>>>(w1, wT1);
        prep_w_kernel<3, 256, 256, 128><<<dim3((3 * 128 * 256 + 255) / 256), blk, 0, stream>>>(w2, wT2);
        prep_w_kernel<3, 128, 128, 64><<<dim3((3 * 64 * 128 + 255) / 256), blk, 0, stream>>>(w3, wT3);
    }

    // MFMA conv stack
    conv_mfma_kernel<4, 5, 5, 160, 256><<<dim3(13, BB), blk, 0, stream>>>(
        xpT1, 212, wT1, b1, xpT2, 210, 1);
    conv_mfma_kernel<2, 3, 8, 256, 128><<<dim3(13, BB), blk, 0, stream>>>(
        xpT2, 210, wT2, b2, xpT3, 210, 1);
    conv_mfma_kernel<1, 3, 4, 128, 64><<<dim3(13, BB), blk, 0, stream>>>(
        xpT3, 210, wT3, b3, xpT4, 200, 0);

    head_kernel<<<dim3(BB), blk, 0, stream>>>(xpT4, w4, b4, control, avg_shape, bf_out);
    locw_kernel<<<dim3(5, BB), blk, 0, stream>>>(control, loc_w);
    fbins_kernel<<<dim3((NBINS + 255) / 256), blk, 0, stream>>>(fbins);

    // fused four-step FFT pipeline (N = 240 x 200)
    passA_kernel<<<dim3(13, BB), blk, 0, stream>>>(wn, I);
    passB_kernel<0><<<dim3(30, BB), blk, 0, stream>>>(I, avg_shape, fbins, loc_w, acc, z0);
    finalize_scale<<<1, 64, 0, stream>>>(acc, z0, scale);
    passC_kernel<<<dim3(13, BB), blk, 0, stream>>>(I, control, f0, scale);
    passB_kernel<1><<<dim3(30, BB), blk, 0, stream>>>(I, avg_shape, fbins, loc_w, acc, z0);
    passD_kernel<<<dim3(13, BB), blk, 0, stream>>>(I, filtered);
}

// Round 6
// 441.749 us; speedup vs baseline: 3.8425x; 1.1028x over previous
//
#include <hip/hip_runtime.h>
#include <math.h>

#define BB 64
#define T_FR 200
#define NA 48000
#define NBINS 24001

typedef __attribute__((ext_vector_type(4))) float f32x4;
typedef __attribute__((ext_vector_type(8))) short bf16x8;

__device__ __forceinline__ unsigned short f2bf(float x)
{
    unsigned u = __float_as_uint(x);
    u = (u + 0x7FFFu + ((u >> 16) & 1u)) >> 16;
    return (unsigned short)u;
}
__device__ __forceinline__ float bf2f(unsigned short h)
{
    return __uint_as_float(((unsigned)h) << 16);
}

__device__ inline float2 cmul(float2 a, float2 b)
{
    return make_float2(a.x * b.x - a.y * b.y, a.x * b.y + a.y * b.x);
}

// e^{2*pi*i*rev} via HW transcendentals: v_sin_f32/v_cos_f32 take REVOLUTIONS.
// Valid |rev| <= 256; our args are < 16.
__device__ __forceinline__ float2 cis_rev(float rev)
{
    return make_float2(__builtin_amdgcn_cosf(rev), __builtin_amdgcn_sinf(rev));
}

// ================= MFMA conv =================
template<int NT, int TAPS, int CHUNKS, int CINP, int COUTP>
__global__ __launch_bounds__(256) void conv_mfma_kernel(
    const unsigned short* __restrict__ xT, int tRowsIn,
    const unsigned short* __restrict__ wT,
    const float* __restrict__ bias,
    unsigned short* __restrict__ outT, int tRowsOut, int tOffOut)
{
    const int b = blockIdx.y;
    const int t0 = blockIdx.x * 16;
    const int tid = threadIdx.x;
    const int wave = tid >> 6;
    const int lane = tid & 63;
    const int m = lane & 15;
    const int quad = lane >> 4;
    const int n0 = wave * (NT * 16);

    f32x4 acc[NT];
#pragma unroll
    for (int nt = 0; nt < NT; ++nt) acc[nt] = (f32x4){0.f, 0.f, 0.f, 0.f};

    const unsigned short* xb = xT + (size_t)b * tRowsIn * CINP;
#pragma unroll
    for (int kw = 0; kw < TAPS; ++kw) {
        const unsigned short* wk = wT + (size_t)kw * COUTP * CINP;
        const unsigned short* xrow = xb + (size_t)(t0 + kw + m) * CINP + quad * 8;
#pragma unroll
        for (int ch = 0; ch < CHUNKS; ++ch) {
            const int k0 = ch * 32;
            bf16x8 a = *(const bf16x8*)(xrow + k0);
#pragma unroll
            for (int nt = 0; nt < NT; ++nt) {
                bf16x8 bfr = *(const bf16x8*)(wk + (size_t)(n0 + nt * 16 + m) * CINP + k0 + quad * 8);
                acc[nt] = __builtin_amdgcn_mfma_f32_16x16x32_bf16(a, bfr, acc[nt], 0, 0, 0);
            }
        }
    }
#pragma unroll
    for (int nt = 0; nt < NT; ++nt) {
        const int n = n0 + nt * 16 + m;
        const float bz = bias[n];
#pragma unroll
        for (int r = 0; r < 4; ++r) {
            const int t = t0 + quad * 4 + r;
            if (t < 200) {
                float v = acc[nt][r] + bz;
                v = (v >= 0.f) ? v : 0.1f * v;
                outT[((size_t)b * tRowsOut + t + tOffOut) * COUTP + n] = f2bf(v);
            }
        }
    }
}

__global__ void prep_x1_kernel(const float* __restrict__ cond, const float* __restrict__ f0,
                               unsigned short* __restrict__ xpT1)
{
    int idx = blockIdx.x * 256 + threadIdx.x;
    const int total = BB * 212 * 160;
    if (idx >= total) return;
    int i = idx % 160;
    int rest = idx / 160;
    int tp = rest % 212;
    int b = rest / 212;
    int tt = tp - 2;
    float v = 0.f;
    if (tt >= 0 && tt < 200) {
        if (i < 128) v = cond[((size_t)b * 128 + i) * 200 + tt];
        else if (i == 128) v = (f0[b * 200 + tt] > 0.f) ? 1.f : 0.f;
    }
    xpT1[idx] = f2bf(v);
}

template<int TAPS, int CINR, int CINP, int COUTP>
__global__ void prep_w_kernel(const float* __restrict__ w, unsigned short* __restrict__ wT)
{
    int idx = blockIdx.x * 256 + threadIdx.x;
    const int total = TAPS * COUTP * CINP;
    if (idx >= total) return;
    int i = idx % CINP;
    int rest = idx / CINP;
    int o = rest % COUTP;
    int kw = rest / COUTP;
    float v = (i < CINR) ? w[((size_t)o * CINR + i) * TAPS + kw] : 0.f;
    wT[idx] = f2bf(v);
}

__global__ void zero16_kernel(uint4* __restrict__ p, int n16)
{
    int idx = blockIdx.x * 256 + threadIdx.x;
    if (idx < n16) p[idx] = make_uint4(0, 0, 0, 0);
}

// ================= FFT =================
template<int R> __device__ __forceinline__ void fill_roots(float (&cr)[R], float (&si)[R]);
template<> __device__ __forceinline__ void fill_roots<8>(float (&cr)[8], float (&si)[8])
{
    const float C = 0.70710678118654752f;
    cr[0]=1.f; cr[1]=C;  cr[2]=0.f;  cr[3]=-C; cr[4]=-1.f; cr[5]=-C;  cr[6]=0.f;  cr[7]=C;
    si[0]=0.f; si[1]=C;  si[2]=1.f;  si[3]=C;  si[4]=0.f;  si[5]=-C;  si[6]=-1.f; si[7]=-C;
}
template<> __device__ __forceinline__ void fill_roots<6>(float (&cr)[6], float (&si)[6])
{
    const float S = 0.86602540378443865f;
    cr[0]=1.f; cr[1]=0.5f; cr[2]=-0.5f; cr[3]=-1.f; cr[4]=-0.5f; cr[5]=0.5f;
    si[0]=0.f; si[1]=S;    si[2]=S;     si[3]=0.f;  si[4]=-S;    si[5]=-S;
}
template<> __device__ __forceinline__ void fill_roots<5>(float (&cr)[5], float (&si)[5])
{
    cr[0]=1.f; cr[1]=0.30901699437494742f; cr[2]=-0.80901699437494742f;
    cr[3]=-0.80901699437494742f; cr[4]=0.30901699437494742f;
    si[0]=0.f; si[1]=0.95105651629515357f; si[2]=0.58778525229247313f;
    si[3]=-0.58778525229247313f; si[4]=-0.95105651629515357f;
}

// reads src[q + SS*p + (LEN/R)*r], writes dst[q + SS*(R*p+rp)],
// twiddle e^{SIGNI*2pi*i*(p*rp/NN + ((r*rp)%R)/R)}.  NN==R => p==0 (no twiddle).
template<int SIGNI, int R, int NN, int SS, int LEN, int STRIDE, int NC>
__device__ __forceinline__ void lds_stage(const float2* __restrict__ src,
                                          float2* __restrict__ dst, int tid)
{
    constexpr int WORK = LEN / R;
    float cr[R], si[R];
    fill_roots<R>(cr, si);
    for (int idx = tid; idx < WORK * NC; idx += 256) {
        int col = idx / WORK;
        int t = idx - col * WORK;
        int p = t / SS, q = t - p * SS;
        const float2* sc = src + col * STRIDE;
        float2* dc = dst + col * STRIDE;
        float2 v[R];
#pragma unroll
        for (int r = 0; r < R; ++r) v[r] = sc[q + SS * p + WORK * r];
        float rev0 = (NN != R) ? (float)(SIGNI * p) / (float)NN : 0.f;
        int ob = q + SS * R * p;
#pragma unroll
        for (int rp = 0; rp < R; ++rp) {
            float re = 0.f, im = 0.f;
#pragma unroll
            for (int r = 0; r < R; ++r) {
                int mm = (r * rp) % R;
                float ure = cr[mm];
                float uim = (SIGNI > 0) ? si[mm] : -si[mm];
                re += v[r].x * ure - v[r].y * uim;
                im += v[r].x * uim + v[r].y * ure;
            }
            float2 o = make_float2(re, im);
            if (NN != R) o = cmul(o, cis_rev(rev0 * (float)rp));
            dc[ob + SS * rp] = o;
        }
    }
}

// 240 = 8*6*5 ; result lands in B.  NC columns, stride 241.
template<int SIGNI, int NC>
__device__ __forceinline__ void fft240(float2* A, float2* B, int tid)
{
    lds_stage<SIGNI, 8, 240, 1, 240, 241, NC>(A, B, tid); __syncthreads();
    lds_stage<SIGNI, 6, 30, 8, 240, 241, NC>(B, A, tid); __syncthreads();
    lds_stage<SIGNI, 5, 5, 48, 240, 241, NC>(A, B, tid); __syncthreads();
}

// 200 = 8*5*5 ; result lands in B.
template<int SIGNI>
__device__ __forceinline__ void fft200(float2* A, float2* B, int tid)
{
    lds_stage<SIGNI, 8, 200, 1, 200, 201, 8>(A, B, tid); __syncthreads();
    lds_stage<SIGNI, 5, 25, 8, 200, 201, 8>(B, A, tid); __syncthreads();
    lds_stage<SIGNI, 5, 5, 40, 200, 201, 8>(A, B, tid); __syncthreads();
}

#define CW 8   // column tile for 240-length passes

// ---------------- pass A: wn -> I[b][k1][n2] = tw * FFT240_n1(x[200*n1+n2]) ----------------
__global__ __launch_bounds__(256) void passA_kernel(const float* __restrict__ wn,
                                                    float2* __restrict__ I)
{
    __shared__ float2 La[CW * 241], Lb[CW * 241];
    int b = blockIdx.y;
    int n20 = blockIdx.x * CW;
    int cc = min(CW, 200 - n20);
    int tid = threadIdx.x;
    for (int idx = tid; idx < 240 * CW; idx += 256) {
        int n1 = idx >> 3, j = idx & 7;
        float v = 0.f;
        if (j < cc) v = wn[(size_t)b * NA + n1 * 200 + n20 + j];
        La[j * 241 + n1] = make_float2(v, 0.f);
    }
    __syncthreads();
    fft240<-1, CW>(La, Lb, tid);
    for (int idx = tid; idx < 240 * CW; idx += 256) {
        int k1 = idx >> 3, j = idx & 7;
        if (j >= cc) continue;
        int n2 = n20 + j;
        int a = (n2 * k1) % NA;
        float2 tw = cis_rev(-(float)a / (float)NA);
        I[(size_t)b * NA + k1 * 200 + n2] = cmul(Lb[j * 241 + k1], tw);
    }
}

// ---------------- pass B: per k1-row: FFT200 fwd -> spectral mul -> FFT200 inv -> tw ----------------
template<int MODE>
__global__ __launch_bounds__(256) void passB_kernel(float2* __restrict__ I,
    const float* __restrict__ avg_shape, const float* __restrict__ fbins,
    const float* __restrict__ loc_w, float* __restrict__ acc, float* __restrict__ z0)
{
    __shared__ float2 La[8 * 201], Lb[8 * 201];
    __shared__ float gsh[32];
    __shared__ float red[256];
    int b = blockIdx.y;
    int row0 = blockIdx.x * 8;
    int tid = threadIdx.x;
    if (MODE == 0) { if (tid < 32) gsh[tid] = avg_shape[b * 32 + tid]; }
    else           { if (tid < 5)  gsh[tid] = loc_w[b * 5 + tid]; }
    for (int idx = tid; idx < 8 * 200; idx += 256) {
        int row = idx / 200, e = idx - row * 200;
        La[row * 201 + e] = I[(size_t)b * NA + (row0 + row) * 200 + e];
    }
    __syncthreads();
    fft200<-1>(La, Lb, tid);
    float part = 0.f;
    for (int idx = tid; idx < 8 * 200; idx += 256) {
        int row = idx / 200, k2 = idx - row * 200;
        int k1 = row0 + row;
        int k = k1 + 240 * k2;
        int kbin = min(k, NA - k);
        float2 X = Lb[row * 201 + k2];
        if (MODE == 0) {
            int j = (kbin * 32) / NBINS;
            if (j < 31 && (NBINS * (j + 1)) / 32 <= kbin) ++j;
            float g = gsh[j];
            float2 Z = make_float2(X.x * g, X.y * g);
            part += Z.x * Z.x + Z.y * Z.y;
            if (k == 0) z0[b] = Z.x;
            Lb[row * 201 + k2] = make_float2(Z.x * (1.f / NA), Z.y * (1.f / NA));
        } else {
            float tf = 0.f;
#pragma unroll
            for (int c = 0; c < 5; ++c) tf += gsh[c] * fbins[c * NBINS + kbin];
            tf *= (1.f / NA);
            Lb[row * 201 + k2] = make_float2(X.x * tf, X.y * tf);
        }
    }
    if (MODE == 0) {
        red[tid] = part;
        __syncthreads();
        for (int st = 128; st > 0; st >>= 1) {
            if (tid < st) red[tid] += red[tid + st];
            __syncthreads();
        }
        if (tid == 0) atomicAdd(&acc[b], red[0]);
    }
    __syncthreads();
    fft200<+1>(Lb, La, tid);
    for (int idx = tid; idx < 8 * 200; idx += 256) {
        int row = idx / 200, n2 = idx - row * 200;
        int k1 = row0 + row;
        int a = (n2 * k1) % NA;
        float2 tw = cis_rev((float)a / (float)NA);
        I[(size_t)b * NA + k1 * 200 + n2] = cmul(La[row * 201 + n2], tw);
    }
}

// ---------------- pass C: inv FFT240 (shaped y) -> scale*mod -> fwd FFT240 + tw ----------------
__global__ __launch_bounds__(256) void passC_kernel(float2* __restrict__ I,
    const float* __restrict__ control, const float* __restrict__ f0,
    const float* __restrict__ scale)
{
    __shared__ float2 La[CW * 241], Lb[CW * 241];
    __shared__ float ctl3[600];
    __shared__ float f0s[200];
    int b = blockIdx.y;
    int n20 = blockIdx.x * CW;
    int cc = min(CW, 200 - n20);
    int tid = threadIdx.x;
    for (int i = tid; i < 600; i += 256) ctl3[i] = control[(size_t)b * 1600 + i];
    for (int i = tid; i < 200; i += 256) f0s[i] = f0[b * 200 + i];
    for (int idx = tid; idx < 240 * CW; idx += 256) {
        int k1 = idx >> 3, j = idx & 7;
        float2 v = make_float2(0.f, 0.f);
        if (j < cc) v = I[(size_t)b * NA + k1 * 200 + n20 + j];
        La[j * 241 + k1] = v;
    }
    __syncthreads();
    fft240<+1, CW>(La, Lb, tid);
    float sc = scale[b];
    for (int idx = tid; idx < 240 * CW; idx += 256) {
        int n1 = idx >> 3, j = idx & 7;
        int n2 = n20 + j;
        int n = 200 * n1 + n2;
        float sf = ((float)n + 0.5f) * (1.f / 240.f) - 0.5f;
        sf = fminf(fmaxf(sf, 0.f), 199.f);
        int i0 = (int)sf;
        int i1 = min(i0 + 1, 199);
        float w = sf - (float)i0;
        float inh = ctl3[i0] * (1.f - w) + ctl3[i1] * w;
        float exh = ctl3[200 + i0] * (1.f - w) + ctl3[200 + i1] * w;
        float pr  = ctl3[400 + i0] * (1.f - w) + ctl3[400 + i1] * w;
        float v0 = f0s[i0] > 0.f ? 1.f : 0.f;
        float v1 = f0s[i1] > 0.f ? 1.f : 0.f;
        float vv = v0 * (1.f - w) + v1 * w;
        float m = inh * (1.f - vv) + exh * pr;
        float y = Lb[j * 241 + n1].x * sc;
        La[j * 241 + n1] = make_float2(y * m, 0.f);
    }
    __syncthreads();
    fft240<-1, CW>(La, Lb, tid);
    for (int idx = tid; idx < 240 * CW; idx += 256) {
        int k1 = idx >> 3, j = idx & 7;
        if (j >= cc) continue;
        int n2 = n20 + j;
        int a = (n2 * k1) % NA;
        float2 tw = cis_rev(-(float)a / (float)NA);
        I[(size_t)b * NA + k1 * 200 + n2] = cmul(Lb[j * 241 + k1], tw);
    }
}

// ---------------- pass D: inv FFT240 -> real audio out ----------------
__global__ __launch_bounds__(256) void passD_kernel(const float2* __restrict__ I,
                                                    float* __restrict__ out)
{
    __shared__ float2 La[CW * 241], Lb[CW * 241];
    int b = blockIdx.y;
    int n20 = blockIdx.x * CW;
    int cc = min(CW, 200 - n20);
    int tid = threadIdx.x;
    for (int idx = tid; idx < 240 * CW; idx += 256) {
        int k1 = idx >> 3, j = idx & 7;
        float2 v = make_float2(0.f, 0.f);
        if (j < cc) v = I[(size_t)b * NA + k1 * 200 + n20 + j];
        La[j * 241 + k1] = v;
    }
    __syncthreads();
    fft240<+1, CW>(La, Lb, tid);
    for (int idx = tid; idx < 240 * CW; idx += 256) {
        int n1 = idx >> 3, j = idx & 7;
        if (j >= cc) continue;
        out[(size_t)b * NA + 200 * n1 + n20 + j] = Lb[j * 241 + n1].x;
    }
}

__global__ void init_kernel(float* __restrict__ acc, float* __restrict__ z0)
{
    int i = threadIdx.x;
    if (i < 64) { acc[i] = 0.f; z0[i] = 0.f; }
}

__global__ void finalize_scale(const float* __restrict__ acc, const float* __restrict__ z0,
                               float* __restrict__ scale)
{
    int b = threadIdx.x;
    if (b < 64) {
        float var = (acc[b] - z0[b] * z0[b]) / (48000.f * 47999.f);
        scale[b] = 0.1f / sqrtf(var);
    }
}

// ---------------- head ----------------
__global__ void head_kernel(const unsigned short* __restrict__ h3T, const float* __restrict__ w4,
                            const float* __restrict__ b4, float* __restrict__ control,
                            float* __restrict__ avg_shape, float* __restrict__ out_bf)
{
    __shared__ float w4s[40 * 64];
    __shared__ float b4s[40];
    __shared__ float sp[200 * 33];
    int b = blockIdx.x;
    for (int j = threadIdx.x; j < 40 * 64; j += 256) w4s[j] = w4[j];
    if (threadIdx.x < 40) b4s[threadIdx.x] = b4[threadIdx.x];
    __syncthreads();
    int t = threadIdx.x;
    if (t < 200) {
        float p[40];
#pragma unroll
        for (int o = 0; o < 40; ++o) p[o] = b4s[o];
        const unsigned short* hb = h3T + ((size_t)b * 200 + t) * 64;
        for (int i = 0; i < 64; ++i) {
            float h = bf2f(hb[i]);
#pragma unroll
            for (int o = 0; o < 40; ++o) p[o] += h * w4s[o * 64 + i];
        }
        float inh = 1.f / (1.f + expf(-p[0]));
        float exh = 1.f / (1.f + expf(-p[1]));
        float pr  = 1.f / (1.f + expf(-p[2]));
        float mx = p[3];
#pragma unroll
        for (int c = 1; c < 32; ++c) mx = fmaxf(mx, p[3 + c]);
        float e[32];
        float sum = 0.f;
#pragma unroll
        for (int c = 0; c < 32; ++c) { e[c] = expf(p[3 + c] - mx); sum += e[c]; }
        float inv = 1.f / sum;
#pragma unroll
        for (int c = 0; c < 32; ++c) sp[t * 33 + c] = e[c] * inv;
        float mx2 = p[35];
#pragma unroll
        for (int c = 1; c < 5; ++c) mx2 = fmaxf(mx2, p[35 + c]);
        float e2[5];
        float s2 = 0.f;
#pragma unroll
        for (int c = 0; c < 5; ++c) { e2[c] = expf(p[35 + c] - mx2); s2 += e2[c]; }
        float inv2 = 1.f / s2;
        float* ctl = control + (size_t)b * 8 * 200;
        ctl[0 * 200 + t] = inh;
        ctl[1 * 200 + t] = exh;
        ctl[2 * 200 + t] = pr;
#pragma unroll
        for (int c = 0; c < 5; ++c) ctl[(3 + c) * 200 + t] = e2[c] * inv2;
        float* bf = out_bf + (size_t)b * 3 * 200;
        bf[0 * 200 + t] = pr;
        bf[1 * 200 + t] = inh;
        bf[2 * 200 + t] = exh;
    }
    __syncthreads();
    if (t < 32) {
        float s = 0.f;
        for (int j = 0; j < 200; ++j) s += sp[j * 33 + t];
        avg_shape[b * 32 + t] = s * (1.f / 200.f);
    }
}

__global__ void locw_kernel(const float* __restrict__ control, float* __restrict__ loc_w)
{
    int c = blockIdx.x, b = blockIdx.y;
    const float* src = control + ((size_t)b * 8 + 3 + c) * 200;
    float s = 0.f;
    for (int i = threadIdx.x; i < NA; i += 256) {
        float sf = (i + 0.5f) * (200.0f / 48000.0f) - 0.5f;
        sf = fminf(fmaxf(sf, 0.f), 199.f);
        int i0 = (int)sf;
        int i1 = min(i0 + 1, 199);
        float w = sf - (float)i0;
        s += src[i0] * (1.f - w) + src[i1] * w;
    }
    __shared__ float red[256];
    red[threadIdx.x] = s;
    __syncthreads();
    for (int st = 128; st > 0; st >>= 1) {
        if (threadIdx.x < st) red[threadIdx.x] += red[threadIdx.x + st];
        __syncthreads();
    }
    if (threadIdx.x == 0) loc_w[b * 5 + c] = red[0] * (1.f / 48000.f);
}

__device__ inline float filter_shape_val(int c, int i)
{
    float lin = (float)i * (1.f / 31.f);
    if (c == 0) { float z = (lin - 0.2f) * 10.f;          return expf(-0.5f * z * z); }
    if (c == 1) { float z = (lin - 0.1f) * 10.f;          return expf(-0.5f * z * z); }
    if (c == 2) { float z = (lin - 0.4f) * (1.f / 0.15f); return expf(-0.5f * z * z); }
    if (c == 3) { float z = (lin - 0.6f) * 10.f;          return expf(-0.5f * z * z); }
    float v = 0.1f + 0.9f * lin;
    return v * v;
}

__global__ void fbins_kernel(float* __restrict__ fbins)
{
    int k = blockIdx.x * 256 + threadIdx.x;
    if (k >= NBINS) return;
    float sf = (k + 0.5f) * (32.0f / 24001.0f) - 0.5f;
    sf = fminf(fmaxf(sf, 0.f), 31.f);
    int i0 = (int)sf;
    int i1 = min(i0 + 1, 31);
    float w = sf - (float)i0;
#pragma unroll
    for (int c = 0; c < 5; ++c)
        fbins[c * NBINS + k] = filter_shape_val(c, i0) * (1.f - w) + filter_shape_val(c, i1) * w;
}

extern "C" void kernel_launch(void* const* d_in, const int* in_sizes, int n_in,
                              void* d_out, int out_size, void* d_ws, size_t ws_size,
                              hipStream_t stream)
{
    const float* cond = (const float*)d_in[0];
    const float* f0   = (const float*)d_in[1];
    const float* wn   = (const float*)d_in[2];
    const float* w1   = (const float*)d_in[3];
    const float* b1   = (const float*)d_in[4];
    const float* w2   = (const float*)d_in[5];
    const float* b2   = (const float*)d_in[6];
    const float* w3   = (const float*)d_in[7];
    const float* b3   = (const float*)d_in[8];
    const float* w4   = (const float*)d_in[9];
    const float* b4   = (const float*)d_in[10];

    float* out = (float*)d_out;
    float* filtered = out;
    float* bf_out   = out + (size_t)BB * NA;

    char* ws = (char*)d_ws;
    size_t off = 0;
    float2* I = (float2*)(ws + off);            off += 24576000;
    unsigned short* xpT1 = (unsigned short*)(ws + off); off += (size_t)BB * 212 * 160 * 2;
    unsigned short* xpT2 = (unsigned short*)(ws + off); off += (size_t)BB * 210 * 256 * 2;
    unsigned short* xpT3 = (unsigned short*)(ws + off); off += (size_t)BB * 210 * 128 * 2;
    unsigned short* xpT4 = (unsigned short*)(ws + off); off += (size_t)BB * 200 * 64 * 2;
    unsigned short* wT1  = (unsigned short*)(ws + off); off += (size_t)5 * 256 * 160 * 2;
    unsigned short* wT2  = (unsigned short*)(ws + off); off += (size_t)3 * 128 * 256 * 2;
    unsigned short* wT3  = (unsigned short*)(ws + off); off += (size_t)3 * 64 * 128 * 2;
    float* control   = (float*)(ws + off);
    float* avg_shape = control + 102400;
    float* loc_w     = avg_shape + 2048;
    float* acc       = loc_w + 320;
    float* z0        = acc + 64;
    float* scale     = z0 + 64;
    float* fbins     = scale + 64;

    dim3 blk(256);

    init_kernel<<<1, 64, 0, stream>>>(acc, z0);

    // prep
    {
        int n1 = BB * 212 * 160;
        prep_x1_kernel<<<dim3((n1 + 255) / 256), blk, 0, stream>>>(cond, f0, xpT1);
        int z2 = (BB * 210 * 256 * 2) / 16;
        zero16_kernel<<<dim3((z2 + 255) / 256), blk, 0, stream>>>((uint4*)xpT2, z2);
        int z3 = (BB * 210 * 128 * 2) / 16;
        zero16_kernel<<<dim3((z3 + 255) / 256), blk, 0, stream>>>((uint4*)xpT3, z3);
        prep_w_kernel<5, 129, 160, 256><<<dim3((5 * 256 * 160 + 255) / 256), blk, 0, stream>>>(w1, wT1);
        prep_w_kernel<3, 256, 256, 128><<<dim3((3 * 128 * 256 + 255) / 256), blk, 0, stream>>>(w2, wT2);
        prep_w_kernel<3, 128, 128, 64><<<dim3((3 * 64 * 128 + 255) / 256), blk, 0, stream>>>(w3, wT3);
    }

    // MFMA conv stack
    conv_mfma_kernel<4, 5, 5, 160, 256><<<dim3(13, BB), blk, 0, stream>>>(
        xpT1, 212, wT1, b1, xpT2, 210, 1);
    conv_mfma_kernel<2, 3, 8, 256, 128><<<dim3(13, BB), blk, 0, stream>>>(
        xpT2, 210, wT2, b2, xpT3, 210, 1);
    conv_mfma_kernel<1, 3, 4, 128, 64><<<dim3(13, BB), blk, 0, stream>>>(
        xpT3, 210, wT3, b3, xpT4, 200, 0);

    head_kernel<<<dim3(BB), blk, 0, stream>>>(xpT4, w4, b4, control, avg_shape, bf_out);
    locw_kernel<<<dim3(5, BB), blk, 0, stream>>>(control, loc_w);
    fbins_kernel<<<dim3((NBINS + 255) / 256), blk, 0, stream>>>(fbins);

    // fused four-step FFT pipeline (N = 240 x 200)
    passA_kernel<<<dim3(25, BB), blk, 0, stream>>>(wn, I);
    passB_kernel<0><<<dim3(30, BB), blk, 0, stream>>>(I, avg_shape, fbins, loc_w, acc, z0);
    finalize_scale<<<1, 64, 0, stream>>>(acc, z0, scale);
    passC_kernel<<<dim3(25, BB), blk, 0, stream>>>(I, control, f0, scale);
    passB_kernel<1><<<dim3(30, BB), blk, 0, stream>>>(I, avg_shape, fbins, loc_w, acc, z0);
    passD_kernel<<<dim3(25, BB), blk, 0, stream>>>(I, filtered);
}

// Round 7
// 417.394 us; speedup vs baseline: 4.0667x; 1.0583x over previous
//
#include <hip/hip_runtime.h>
#include <math.h>

#define BB 64
#define T_FR 200
#define NA 48000
#define NBINS 24001

typedef __attribute__((ext_vector_type(4))) float f32x4;
typedef __attribute__((ext_vector_type(8))) short bf16x8;

__device__ __forceinline__ unsigned short f2bf(float x)
{
    unsigned u = __float_as_uint(x);
    u = (u + 0x7FFFu + ((u >> 16) & 1u)) >> 16;
    return (unsigned short)u;
}
__device__ __forceinline__ float bf2f(unsigned short h)
{
    return __uint_as_float(((unsigned)h) << 16);
}

__device__ inline float2 cmul(float2 a, float2 b)
{
    return make_float2(a.x * b.x - a.y * b.y, a.x * b.y + a.y * b.x);
}

// e^{2*pi*i*rev} via HW transcendentals (args in revolutions, |rev|<1 here)
__device__ __forceinline__ float2 cis_rev(float rev)
{
    return make_float2(__builtin_amdgcn_cosf(rev), __builtin_amdgcn_sinf(rev));
}

// ---------------- compile-time root tables ----------------
template<int R> __device__ __forceinline__ void fill_roots(float (&cr)[R], float (&si)[R]);
template<> __device__ __forceinline__ void fill_roots<3>(float (&cr)[3], float (&si)[3])
{
    const float S = 0.86602540378443865f;
    cr[0]=1.f; cr[1]=-0.5f; cr[2]=-0.5f;
    si[0]=0.f; si[1]=S;     si[2]=-S;
}
template<> __device__ __forceinline__ void fill_roots<4>(float (&cr)[4], float (&si)[4])
{
    cr[0]=1.f; cr[1]=0.f; cr[2]=-1.f; cr[3]=0.f;
    si[0]=0.f; si[1]=1.f; si[2]=0.f;  si[3]=-1.f;
}
template<> __device__ __forceinline__ void fill_roots<5>(float (&cr)[5], float (&si)[5])
{
    cr[0]=1.f; cr[1]=0.30901699437494742f; cr[2]=-0.80901699437494742f;
    cr[3]=-0.80901699437494742f; cr[4]=0.30901699437494742f;
    si[0]=0.f; si[1]=0.95105651629515357f; si[2]=0.58778525229247313f;
    si[3]=-0.58778525229247313f; si[4]=-0.95105651629515357f;
}
template<> __device__ __forceinline__ void fill_roots<8>(float (&cr)[8], float (&si)[8])
{
    const float C = 0.70710678118654752f;
    cr[0]=1.f; cr[1]=C;  cr[2]=0.f;  cr[3]=-C; cr[4]=-1.f; cr[5]=-C;  cr[6]=0.f;  cr[7]=C;
    si[0]=0.f; si[1]=C;  si[2]=1.f;  si[3]=C;  si[4]=0.f;  si[5]=-C;  si[6]=-1.f; si[7]=-C;
}

// generic direct R-point DFT in registers (S=-1 fwd, +1 inv)
template<int S, int R>
__device__ __forceinline__ void dftR(float2 (&v)[R])
{
    float cr[R], si[R];
    fill_roots<R>(cr, si);
    float2 o[R];
#pragma unroll
    for (int k = 0; k < R; ++k) {
        float re = 0.f, im = 0.f;
#pragma unroll
        for (int j = 0; j < R; ++j) {
            int m = (j * k) % R;
            float ur = cr[m], ui = (S > 0) ? si[m] : -si[m];
            re += v[j].x * ur - v[j].y * ui;
            im += v[j].x * ui + v[j].y * ur;
        }
        o[k] = make_float2(re, im);
    }
#pragma unroll
    for (int k = 0; k < R; ++k) v[k] = o[k];
}

// twiddle tables (literal): e^{2pi m / N}
__device__ __constant__ float C25R[17] = {1.f,0.968583161f,0.876306680f,0.728968627f,0.535826795f,0.309016994f,0.062790520f,-0.187381315f,-0.425779292f,-0.637423990f,-0.809016994f,-0.929776486f,-0.992114701f,-0.992114701f,-0.929776486f,-0.809016994f,-0.637423990f};
__device__ __constant__ float C25I[17] = {0.f,0.248689887f,0.481753674f,0.684547106f,0.844327926f,0.951056516f,0.998026728f,0.982287251f,0.904827052f,0.770513243f,0.587785252f,0.368124553f,0.125333234f,-0.125333234f,-0.368124553f,-0.587785252f,-0.770513243f};
__device__ __constant__ float C15R[9] = {1.f,0.913545458f,0.669130606f,0.309016994f,-0.104528463f,-0.5f,-0.809016994f,-0.978147601f,-0.978147601f};
__device__ __constant__ float C15I[9] = {0.f,0.406736643f,0.743144825f,0.951056516f,0.994521895f,0.866025404f,0.587785252f,0.207911691f,-0.207911691f};
__device__ __constant__ float C16R[10] = {1.f,0.923879533f,0.707106781f,0.382683432f,0.f,-0.382683432f,-0.707106781f,-0.923879533f,-1.f,-0.923879533f};
__device__ __constant__ float C16I[10] = {0.f,0.382683432f,0.707106781f,0.923879533f,1.f,0.923879533f,0.707106781f,0.382683432f,0.f,-0.382683432f};

// 25-point DFT via 5x5 CT (x[5a+b] -> X[c+5d])
template<int S>
__device__ __forceinline__ void dft25(float2 (&v)[25])
{
    float2 t[25];
#pragma unroll
    for (int b = 0; b < 5; ++b) {
        float2 in[5];
#pragma unroll
        for (int a = 0; a < 5; ++a) in[a] = v[5 * a + b];
        dftR<S, 5>(in);
#pragma unroll
        for (int c = 0; c < 5; ++c) {
            int m = b * c;
            float2 w = make_float2(C25R[m], (S > 0) ? C25I[m] : -C25I[m]);
            t[5 * c + b] = cmul(in[c], w);
        }
    }
#pragma unroll
    for (int c = 0; c < 5; ++c) {
        float2 in[5];
#pragma unroll
        for (int bb = 0; bb < 5; ++bb) in[bb] = t[5 * c + bb];
        dftR<S, 5>(in);
#pragma unroll
        for (int d = 0; d < 5; ++d) v[c + 5 * d] = in[d];
    }
}

// 15-point DFT via 5x3 CT (x[3a+b] -> X[c+5d])
template<int S>
__device__ __forceinline__ void dft15(float2 (&v)[15])
{
    float2 t[15];
#pragma unroll
    for (int b = 0; b < 3; ++b) {
        float2 in[5];
#pragma unroll
        for (int a = 0; a < 5; ++a) in[a] = v[3 * a + b];
        dftR<S, 5>(in);
#pragma unroll
        for (int c = 0; c < 5; ++c) {
            int m = b * c;
            float2 w = make_float2(C15R[m], (S > 0) ? C15I[m] : -C15I[m]);
            t[3 * c + b] = cmul(in[c], w);
        }
    }
#pragma unroll
    for (int c = 0; c < 5; ++c) {
        float2 in[3];
#pragma unroll
        for (int bb = 0; bb < 3; ++bb) in[bb] = t[3 * c + bb];
        dftR<S, 3>(in);
#pragma unroll
        for (int d = 0; d < 3; ++d) v[c + 5 * d] = in[d];
    }
}

// 16-point DFT via 4x4 CT (x[4a+b] -> X[c+4d])
template<int S>
__device__ __forceinline__ void dft16(float2 (&v)[16])
{
    float2 t[16];
#pragma unroll
    for (int b = 0; b < 4; ++b) {
        float2 in[4];
#pragma unroll
        for (int a = 0; a < 4; ++a) in[a] = v[4 * a + b];
        dftR<S, 4>(in);
#pragma unroll
        for (int c = 0; c < 4; ++c) {
            int m = b * c;
            float2 w = make_float2(C16R[m], (S > 0) ? C16I[m] : -C16I[m]);
            t[4 * c + b] = cmul(in[c], w);
        }
    }
#pragma unroll
    for (int c = 0; c < 4; ++c) {
        float2 in[4];
#pragma unroll
        for (int bb = 0; bb < 4; ++bb) in[bb] = t[4 * c + bb];
        dftR<S, 4>(in);
#pragma unroll
        for (int d = 0; d < 4; ++d) v[c + 4 * d] = in[d];
    }
}

// ---- fft200 = 8(n1) x 25(n2): x at row[25*n1+n2]; result X at row[k] natural ----
template<int S>
__device__ __forceinline__ void f200_p1(float2* row, int g)   // g = n2 in [0,25)
{
    float2 v[8];
#pragma unroll
    for (int j = 0; j < 8; ++j) v[j] = row[25 * j + g];
    dftR<S, 8>(v);
    float base = (float)S * (float)g * (1.f / 200.f);
#pragma unroll
    for (int k1 = 1; k1 < 8; ++k1) v[k1] = cmul(v[k1], cis_rev(base * (float)k1));
#pragma unroll
    for (int k1 = 0; k1 < 8; ++k1) row[25 * k1 + g] = v[k1];
}

// ---- fft240 = 16(n1) x 15(n2): x at row[15*n1+n2]; result X at row[k] natural ----
template<int S>
__device__ __forceinline__ void f240_p1(float2* row, int g)   // g = n2 in [0,15)
{
    float2 v[16];
#pragma unroll
    for (int j = 0; j < 16; ++j) v[j] = row[15 * j + g];
    dft16<S>(v);
    float base = (float)S * (float)g * (1.f / 240.f);
#pragma unroll
    for (int k1 = 1; k1 < 16; ++k1) v[k1] = cmul(v[k1], cis_rev(base * (float)k1));
#pragma unroll
    for (int k1 = 0; k1 < 16; ++k1) row[15 * k1 + g] = v[k1];
}

// ================= MFMA conv (unchanged) =================
template<int NT, int TAPS, int CHUNKS, int CINP, int COUTP>
__global__ __launch_bounds__(256) void conv_mfma_kernel(
    const unsigned short* __restrict__ xT, int tRowsIn,
    const unsigned short* __restrict__ wT,
    const float* __restrict__ bias,
    unsigned short* __restrict__ outT, int tRowsOut, int tOffOut)
{
    const int b = blockIdx.y;
    const int t0 = blockIdx.x * 16;
    const int tid = threadIdx.x;
    const int wave = tid >> 6;
    const int lane = tid & 63;
    const int m = lane & 15;
    const int quad = lane >> 4;
    const int n0 = wave * (NT * 16);

    f32x4 acc[NT];
#pragma unroll
    for (int nt = 0; nt < NT; ++nt) acc[nt] = (f32x4){0.f, 0.f, 0.f, 0.f};

    const unsigned short* xb = xT + (size_t)b * tRowsIn * CINP;
#pragma unroll
    for (int kw = 0; kw < TAPS; ++kw) {
        const unsigned short* wk = wT + (size_t)kw * COUTP * CINP;
        const unsigned short* xrow = xb + (size_t)(t0 + kw + m) * CINP + quad * 8;
#pragma unroll
        for (int ch = 0; ch < CHUNKS; ++ch) {
            const int k0 = ch * 32;
            bf16x8 a = *(const bf16x8*)(xrow + k0);
#pragma unroll
            for (int nt = 0; nt < NT; ++nt) {
                bf16x8 bfr = *(const bf16x8*)(wk + (size_t)(n0 + nt * 16 + m) * CINP + k0 + quad * 8);
                acc[nt] = __builtin_amdgcn_mfma_f32_16x16x32_bf16(a, bfr, acc[nt], 0, 0, 0);
            }
        }
    }
#pragma unroll
    for (int nt = 0; nt < NT; ++nt) {
        const int n = n0 + nt * 16 + m;
        const float bz = bias[n];
#pragma unroll
        for (int r = 0; r < 4; ++r) {
            const int t = t0 + quad * 4 + r;
            if (t < 200) {
                float v = acc[nt][r] + bz;
                v = (v >= 0.f) ? v : 0.1f * v;
                outT[((size_t)b * tRowsOut + t + tOffOut) * COUTP + n] = f2bf(v);
            }
        }
    }
}

__global__ void prep_x1_kernel(const float* __restrict__ cond, const float* __restrict__ f0,
                               unsigned short* __restrict__ xpT1)
{
    int idx = blockIdx.x * 256 + threadIdx.x;
    const int total = BB * 212 * 160;
    if (idx >= total) return;
    int i = idx % 160;
    int rest = idx / 160;
    int tp = rest % 212;
    int b = rest / 212;
    int tt = tp - 2;
    float v = 0.f;
    if (tt >= 0 && tt < 200) {
        if (i < 128) v = cond[((size_t)b * 128 + i) * 200 + tt];
        else if (i == 128) v = (f0[b * 200 + tt] > 0.f) ? 1.f : 0.f;
    }
    xpT1[idx] = f2bf(v);
}

template<int TAPS, int CINR, int CINP, int COUTP>
__global__ void prep_w_kernel(const float* __restrict__ w, unsigned short* __restrict__ wT)
{
    int idx = blockIdx.x * 256 + threadIdx.x;
    const int total = TAPS * COUTP * CINP;
    if (idx >= total) return;
    int i = idx % CINP;
    int rest = idx / CINP;
    int o = rest % COUTP;
    int kw = rest / COUTP;
    float v = (i < CINR) ? w[((size_t)o * CINR + i) * TAPS + kw] : 0.f;
    wT[idx] = f2bf(v);
}

__global__ void zero16_kernel(uint4* __restrict__ p, int n16)
{
    int idx = blockIdx.x * 256 + threadIdx.x;
    if (idx < n16) p[idx] = make_uint4(0, 0, 0, 0);
}

// ================= FFT passes (register-resident) =================

// pass A: wn -> I[b][k1][n2] = tw * FFT240_n1(x[200*n1+n2]);  16 columns/block
__global__ __launch_bounds__(256) void passA_kernel(const float* __restrict__ wn,
                                                    float2* __restrict__ I)
{
    __shared__ float2 L[16 * 241];
    int b = blockIdx.y;
    int n20 = blockIdx.x * 16;
    int cc = min(16, 200 - n20);
    int tid = threadIdx.x;
    for (int idx = tid; idx < 240 * 16; idx += 256) {
        int n1 = idx >> 4, j = idx & 15;
        float v = (j < cc) ? wn[(size_t)b * NA + n1 * 200 + n20 + j] : 0.f;
        L[j * 241 + n1] = make_float2(v, 0.f);
    }
    __syncthreads();
    if (tid < 240) { int j = tid & 15, g = tid >> 4; f240_p1<-1>(L + j * 241, g); }
    __syncthreads();
    {
        float2 u[15];
        int j = tid & 15, k1 = tid >> 4;
#pragma unroll
        for (int g = 0; g < 15; ++g) u[g] = L[j * 241 + 15 * k1 + g];
        __syncthreads();
        dft15<-1>(u);
#pragma unroll
        for (int k2 = 0; k2 < 15; ++k2) L[j * 241 + k1 + 16 * k2] = u[k2];
    }
    __syncthreads();
    for (int idx = tid; idx < 240 * 16; idx += 256) {
        int k1 = idx >> 4, j = idx & 15;
        if (j >= cc) continue;
        int n2 = n20 + j;
        int a = (n2 * k1) % NA;
        I[(size_t)b * NA + k1 * 200 + n2] = cmul(L[j * 241 + k1], cis_rev(-(float)a / (float)NA));
    }
}

// pass B: 30 rows/block; fwd fft200 -> spectral mul (+Parseval) -> inv fft200 -> tw
template<int MODE>
__global__ __launch_bounds__(256) void passB_kernel(float2* __restrict__ I,
    const float* __restrict__ avg_shape, const float* __restrict__ fbins,
    const float* __restrict__ loc_w, float* __restrict__ acc, float* __restrict__ z0)
{
    __shared__ float2 L[30 * 202];
    __shared__ float gsh[32];
    int b = blockIdx.y;
    int row0 = blockIdx.x * 30;
    int tid = threadIdx.x;
    if (MODE == 0) { if (tid < 32) gsh[tid] = avg_shape[b * 32 + tid]; }
    else           { if (tid < 5)  gsh[tid] = loc_w[b * 5 + tid]; }
    for (int idx = tid; idx < 30 * 200; idx += 256) {
        int row = idx / 200, e = idx - row * 200;
        L[row * 202 + e] = I[(size_t)b * NA + (row0 + row) * 200 + e];
    }
    __syncthreads();
    for (int idx = tid; idx < 750; idx += 256) {
        int row = idx / 25, g = idx - row * 25;
        f200_p1<-1>(L + row * 202, g);
    }
    __syncthreads();
    float part = 0.f;
    {
        float2 u[25];
        int row = tid >> 3, k1 = tid & 7;
        bool act = (tid < 240);
        if (act) {
#pragma unroll
            for (int g = 0; g < 25; ++g) u[g] = L[row * 202 + 25 * k1 + g];
        }
        __syncthreads();
        if (act) {
            dft25<-1>(u);
            int k1_240 = row0 + row;
#pragma unroll
            for (int d = 0; d < 25; ++d) {
                int k2p = k1 + 8 * d;
                int k = k1_240 + 240 * k2p;
                int kbin = min(k, NA - k);
                float2 X = u[d];
                if (MODE == 0) {
                    int jj = (kbin * 32) / NBINS;
                    if (jj < 31 && (NBINS * (jj + 1)) / 32 <= kbin) ++jj;
                    float g2 = gsh[jj];
                    float2 Z = make_float2(X.x * g2, X.y * g2);
                    part += Z.x * Z.x + Z.y * Z.y;
                    if (k == 0) z0[b] = Z.x;
                    u[d] = make_float2(Z.x * (1.f / NA), Z.y * (1.f / NA));
                } else {
                    float tf = 0.f;
#pragma unroll
                    for (int c = 0; c < 5; ++c) tf += gsh[c] * fbins[c * NBINS + kbin];
                    tf *= (1.f / NA);
                    u[d] = make_float2(X.x * tf, X.y * tf);
                }
            }
#pragma unroll
            for (int d = 0; d < 25; ++d) L[row * 202 + k1 + 8 * d] = u[d];
        }
    }
    if (MODE == 0) {
        for (int o = 32; o > 0; o >>= 1) part += __shfl_down(part, o);
        if ((tid & 63) == 0) atomicAdd(&acc[b], part);
    }
    __syncthreads();
    for (int idx = tid; idx < 750; idx += 256) {
        int row = idx / 25, g = idx - row * 25;
        f200_p1<+1>(L + row * 202, g);
    }
    __syncthreads();
    {
        float2 u[25];
        int row = tid >> 3, k1 = tid & 7;
        bool act = (tid < 240);
        if (act) {
#pragma unroll
            for (int g = 0; g < 25; ++g) u[g] = L[row * 202 + 25 * k1 + g];
        }
        __syncthreads();
        if (act) {
            dft25<+1>(u);
#pragma unroll
            for (int d = 0; d < 25; ++d) L[row * 202 + k1 + 8 * d] = u[d];
        }
    }
    __syncthreads();
    for (int idx = tid; idx < 30 * 200; idx += 256) {
        int row = idx / 200, n2 = idx - row * 200;
        int k1 = row0 + row;
        int a = (n2 * k1) % NA;
        I[(size_t)b * NA + k1 * 200 + n2] = cmul(L[row * 202 + n2], cis_rev((float)a / (float)NA));
    }
}

// pass C: inv fft240 -> scale*mod -> fwd fft240 + tw;  16 columns/block
__global__ __launch_bounds__(256) void passC_kernel(float2* __restrict__ I,
    const float* __restrict__ control, const float* __restrict__ f0,
    const float* __restrict__ scale)
{
    __shared__ float2 L[16 * 241];
    __shared__ float ctl3[600];
    __shared__ float f0s[200];
    int b = blockIdx.y;
    int n20 = blockIdx.x * 16;
    int cc = min(16, 200 - n20);
    int tid = threadIdx.x;
    for (int i = tid; i < 600; i += 256) ctl3[i] = control[(size_t)b * 1600 + i];
    for (int i = tid; i < 200; i += 256) f0s[i] = f0[b * 200 + i];
    for (int idx = tid; idx < 240 * 16; idx += 256) {
        int k1 = idx >> 4, j = idx & 15;
        float2 v = make_float2(0.f, 0.f);
        if (j < cc) v = I[(size_t)b * NA + k1 * 200 + n20 + j];
        L[j * 241 + k1] = v;
    }
    __syncthreads();
    if (tid < 240) { int j = tid & 15, g = tid >> 4; f240_p1<+1>(L + j * 241, g); }
    __syncthreads();
    {
        float2 u[15];
        int j = tid & 15, k1 = tid >> 4;
#pragma unroll
        for (int g = 0; g < 15; ++g) u[g] = L[j * 241 + 15 * k1 + g];
        __syncthreads();
        dft15<+1>(u);
#pragma unroll
        for (int k2 = 0; k2 < 15; ++k2) L[j * 241 + k1 + 16 * k2] = u[k2];
    }
    __syncthreads();
    float sc = scale[b];
    for (int idx = tid; idx < 240 * 16; idx += 256) {
        int n1 = idx >> 4, j = idx & 15;
        int n2 = n20 + j;
        int n = 200 * n1 + n2;
        float sf = ((float)n + 0.5f) * (1.f / 240.f) - 0.5f;
        sf = fminf(fmaxf(sf, 0.f), 199.f);
        int i0 = (int)sf;
        int i1 = min(i0 + 1, 199);
        float w = sf - (float)i0;
        float inh = ctl3[i0] * (1.f - w) + ctl3[i1] * w;
        float exh = ctl3[200 + i0] * (1.f - w) + ctl3[200 + i1] * w;
        float pr  = ctl3[400 + i0] * (1.f - w) + ctl3[400 + i1] * w;
        float v0 = f0s[i0] > 0.f ? 1.f : 0.f;
        float v1 = f0s[i1] > 0.f ? 1.f : 0.f;
        float vv = v0 * (1.f - w) + v1 * w;
        float m = inh * (1.f - vv) + exh * pr;
        float y = L[j * 241 + n1].x * sc;
        L[j * 241 + n1] = make_float2(y * m, 0.f);
    }
    __syncthreads();
    if (tid < 240) { int j = tid & 15, g = tid >> 4; f240_p1<-1>(L + j * 241, g); }
    __syncthreads();
    {
        float2 u[15];
        int j = tid & 15, k1 = tid >> 4;
#pragma unroll
        for (int g = 0; g < 15; ++g) u[g] = L[j * 241 + 15 * k1 + g];
        __syncthreads();
        dft15<-1>(u);
#pragma unroll
        for (int k2 = 0; k2 < 15; ++k2) L[j * 241 + k1 + 16 * k2] = u[k2];
    }
    __syncthreads();
    for (int idx = tid; idx < 240 * 16; idx += 256) {
        int k1 = idx >> 4, j = idx & 15;
        if (j >= cc) continue;
        int n2 = n20 + j;
        int a = (n2 * k1) % NA;
        I[(size_t)b * NA + k1 * 200 + n2] = cmul(L[j * 241 + k1], cis_rev(-(float)a / (float)NA));
    }
}

// pass D: inv fft240 -> real audio out
__global__ __launch_bounds__(256) void passD_kernel(const float2* __restrict__ I,
                                                    float* __restrict__ out)
{
    __shared__ float2 L[16 * 241];
    int b = blockIdx.y;
    int n20 = blockIdx.x * 16;
    int cc = min(16, 200 - n20);
    int tid = threadIdx.x;
    for (int idx = tid; idx < 240 * 16; idx += 256) {
        int k1 = idx >> 4, j = idx & 15;
        float2 v = make_float2(0.f, 0.f);
        if (j < cc) v = I[(size_t)b * NA + k1 * 200 + n20 + j];
        L[j * 241 + k1] = v;
    }
    __syncthreads();
    if (tid < 240) { int j = tid & 15, g = tid >> 4; f240_p1<+1>(L + j * 241, g); }
    __syncthreads();
    {
        float2 u[15];
        int j = tid & 15, k1 = tid >> 4;
#pragma unroll
        for (int g = 0; g < 15; ++g) u[g] = L[j * 241 + 15 * k1 + g];
        __syncthreads();
        dft15<+1>(u);
#pragma unroll
        for (int k2 = 0; k2 < 15; ++k2) L[j * 241 + k1 + 16 * k2] = u[k2];
    }
    __syncthreads();
    for (int idx = tid; idx < 240 * 16; idx += 256) {
        int n1 = idx >> 4, j = idx & 15;
        if (j >= cc) continue;
        out[(size_t)b * NA + 200 * n1 + n20 + j] = L[j * 241 + n1].x;
    }
}

__global__ void init_kernel(float* __restrict__ acc, float* __restrict__ z0)
{
    int i = threadIdx.x;
    if (i < 64) { acc[i] = 0.f; z0[i] = 0.f; }
}

__global__ void finalize_scale(const float* __restrict__ acc, const float* __restrict__ z0,
                               float* __restrict__ scale)
{
    int b = threadIdx.x;
    if (b < 64) {
        float var = (acc[b] - z0[b] * z0[b]) / (48000.f * 47999.f);
        scale[b] = 0.1f / sqrtf(var);
    }
}

// ---------------- head ----------------
__global__ void head_kernel(const unsigned short* __restrict__ h3T, const float* __restrict__ w4,
                            const float* __restrict__ b4, float* __restrict__ control,
                            float* __restrict__ avg_shape, float* __restrict__ out_bf)
{
    __shared__ float w4s[40 * 64];
    __shared__ float b4s[40];
    __shared__ float sp[200 * 33];
    int b = blockIdx.x;
    for (int j = threadIdx.x; j < 40 * 64; j += 256) w4s[j] = w4[j];
    if (threadIdx.x < 40) b4s[threadIdx.x] = b4[threadIdx.x];
    __syncthreads();
    int t = threadIdx.x;
    if (t < 200) {
        float p[40];
#pragma unroll
        for (int o = 0; o < 40; ++o) p[o] = b4s[o];
        const unsigned short* hb = h3T + ((size_t)b * 200 + t) * 64;
        for (int i = 0; i < 64; ++i) {
            float h = bf2f(hb[i]);
#pragma unroll
            for (int o = 0; o < 40; ++o) p[o] += h * w4s[o * 64 + i];
        }
        float inh = 1.f / (1.f + expf(-p[0]));
        float exh = 1.f / (1.f + expf(-p[1]));
        float pr  = 1.f / (1.f + expf(-p[2]));
        float mx = p[3];
#pragma unroll
        for (int c = 1; c < 32; ++c) mx = fmaxf(mx, p[3 + c]);
        float e[32];
        float sum = 0.f;
#pragma unroll
        for (int c = 0; c < 32; ++c) { e[c] = expf(p[3 + c] - mx); sum += e[c]; }
        float inv = 1.f / sum;
#pragma unroll
        for (int c = 0; c < 32; ++c) sp[t * 33 + c] = e[c] * inv;
        float mx2 = p[35];
#pragma unroll
        for (int c = 1; c < 5; ++c) mx2 = fmaxf(mx2, p[35 + c]);
        float e2[5];
        float s2 = 0.f;
#pragma unroll
        for (int c = 0; c < 5; ++c) { e2[c] = expf(p[35 + c] - mx2); s2 += e2[c]; }
        float inv2 = 1.f / s2;
        float* ctl = control + (size_t)b * 8 * 200;
        ctl[0 * 200 + t] = inh;
        ctl[1 * 200 + t] = exh;
        ctl[2 * 200 + t] = pr;
#pragma unroll
        for (int c = 0; c < 5; ++c) ctl[(3 + c) * 200 + t] = e2[c] * inv2;
        float* bf = out_bf + (size_t)b * 3 * 200;
        bf[0 * 200 + t] = pr;
        bf[1 * 200 + t] = inh;
        bf[2 * 200 + t] = exh;
    }
    __syncthreads();
    if (t < 32) {
        float s = 0.f;
        for (int j = 0; j < 200; ++j) s += sp[j * 33 + t];
        avg_shape[b * 32 + t] = s * (1.f / 200.f);
    }
}

__global__ void locw_kernel(const float* __restrict__ control, float* __restrict__ loc_w)
{
    int c = blockIdx.x, b = blockIdx.y;
    const float* src = control + ((size_t)b * 8 + 3 + c) * 200;
    float s = 0.f;
    for (int i = threadIdx.x; i < NA; i += 256) {
        float sf = (i + 0.5f) * (200.0f / 48000.0f) - 0.5f;
        sf = fminf(fmaxf(sf, 0.f), 199.f);
        int i0 = (int)sf;
        int i1 = min(i0 + 1, 199);
        float w = sf - (float)i0;
        s += src[i0] * (1.f - w) + src[i1] * w;
    }
    __shared__ float red[256];
    red[threadIdx.x] = s;
    __syncthreads();
    for (int st = 128; st > 0; st >>= 1) {
        if (threadIdx.x < st) red[threadIdx.x] += red[threadIdx.x + st];
        __syncthreads();
    }
    if (threadIdx.x == 0) loc_w[b * 5 + c] = red[0] * (1.f / 48000.f);
}

__device__ inline float filter_shape_val(int c, int i)
{
    float lin = (float)i * (1.f / 31.f);
    if (c == 0) { float z = (lin - 0.2f) * 10.f;          return expf(-0.5f * z * z); }
    if (c == 1) { float z = (lin - 0.1f) * 10.f;          return expf(-0.5f * z * z); }
    if (c == 2) { float z = (lin - 0.4f) * (1.f / 0.15f); return expf(-0.5f * z * z); }
    if (c == 3) { float z = (lin - 0.6f) * 10.f;          return expf(-0.5f * z * z); }
    float v = 0.1f + 0.9f * lin;
    return v * v;
}

__global__ void fbins_kernel(float* __restrict__ fbins)
{
    int k = blockIdx.x * 256 + threadIdx.x;
    if (k >= NBINS) return;
    float sf = (k + 0.5f) * (32.0f / 24001.0f) - 0.5f;
    sf = fminf(fmaxf(sf, 0.f), 31.f);
    int i0 = (int)sf;
    int i1 = min(i0 + 1, 31);
    float w = sf - (float)i0;
#pragma unroll
    for (int c = 0; c < 5; ++c)
        fbins[c * NBINS + k] = filter_shape_val(c, i0) * (1.f - w) + filter_shape_val(c, i1) * w;
}

extern "C" void kernel_launch(void* const* d_in, const int* in_sizes, int n_in,
                              void* d_out, int out_size, void* d_ws, size_t ws_size,
                              hipStream_t stream)
{
    const float* cond = (const float*)d_in[0];
    const float* f0   = (const float*)d_in[1];
    const float* wn   = (const float*)d_in[2];
    const float* w1   = (const float*)d_in[3];
    const float* b1   = (const float*)d_in[4];
    const float* w2   = (const float*)d_in[5];
    const float* b2   = (const float*)d_in[6];
    const float* w3   = (const float*)d_in[7];
    const float* b3   = (const float*)d_in[8];
    const float* w4   = (const float*)d_in[9];
    const float* b4   = (const float*)d_in[10];

    float* out = (float*)d_out;
    float* filtered = out;
    float* bf_out   = out + (size_t)BB * NA;

    char* ws = (char*)d_ws;
    size_t off = 0;
    float2* I = (float2*)(ws + off);            off += 24576000;
    unsigned short* xpT1 = (unsigned short*)(ws + off); off += (size_t)BB * 212 * 160 * 2;
    unsigned short* xpT2 = (unsigned short*)(ws + off); off += (size_t)BB * 210 * 256 * 2;
    unsigned short* xpT3 = (unsigned short*)(ws + off); off += (size_t)BB * 210 * 128 * 2;
    unsigned short* xpT4 = (unsigned short*)(ws + off); off += (size_t)BB * 200 * 64 * 2;
    unsigned short* wT1  = (unsigned short*)(ws + off); off += (size_t)5 * 256 * 160 * 2;
    unsigned short* wT2  = (unsigned short*)(ws + off); off += (size_t)3 * 128 * 256 * 2;
    unsigned short* wT3  = (unsigned short*)(ws + off); off += (size_t)3 * 64 * 128 * 2;
    float* control   = (float*)(ws + off);
    float* avg_shape = control + 102400;
    float* loc_w     = avg_shape + 2048;
    float* acc       = loc_w + 320;
    float* z0        = acc + 64;
    float* scale     = z0 + 64;
    float* fbins     = scale + 64;

    dim3 blk(256);

    init_kernel<<<1, 64, 0, stream>>>(acc, z0);

    // prep
    {
        int n1 = BB * 212 * 160;
        prep_x1_kernel<<<dim3((n1 + 255) / 256), blk, 0, stream>>>(cond, f0, xpT1);
        int z2 = (BB * 210 * 256 * 2) / 16;
        zero16_kernel<<<dim3((z2 + 255) / 256), blk, 0, stream>>>((uint4*)xpT2, z2);
        int z3 = (BB * 210 * 128 * 2) / 16;
        zero16_kernel<<<dim3((z3 + 255) / 256), blk, 0, stream>>>((uint4*)xpT3, z3);
        prep_w_kernel<5, 129, 160, 256><<<dim3((5 * 256 * 160 + 255) / 256), blk, 0, stream>>>(w1, wT1);
        prep_w_kernel<3, 256, 256, 128><<<dim3((3 * 128 * 256 + 255) / 256), blk, 0, stream>>>(w2, wT2);
        prep_w_kernel<3, 128, 128, 64><<<dim3((3 * 64 * 128 + 255) / 256), blk, 0, stream>>>(w3, wT3);
    }

    // MFMA conv stack
    conv_mfma_kernel<4, 5, 5, 160, 256><<<dim3(13, BB), blk, 0, stream>>>(
        xpT1, 212, wT1, b1, xpT2, 210, 1);
    conv_mfma_kernel<2, 3, 8, 256, 128><<<dim3(13, BB), blk, 0, stream>>>(
        xpT2, 210, wT2, b2, xpT3, 210, 1);
    conv_mfma_kernel<1, 3, 4, 128, 64><<<dim3(13, BB), blk, 0, stream>>>(
        xpT3, 210, wT3, b3, xpT4, 200, 0);

    head_kernel<<<dim3(BB), blk, 0, stream>>>(xpT4, w4, b4, control, avg_shape, bf_out);
    locw_kernel<<<dim3(5, BB), blk, 0, stream>>>(control, loc_w);
    fbins_kernel<<<dim3((NBINS + 255) / 256), blk, 0, stream>>>(fbins);

    // fused four-step FFT pipeline (N = 240 x 200), register-resident row FFTs
    passA_kernel<<<dim3(13, BB), blk, 0, stream>>>(wn, I);
    passB_kernel<0><<<dim3(8, BB), blk, 0, stream>>>(I, avg_shape, fbins, loc_w, acc, z0);
    finalize_scale<<<1, 64, 0, stream>>>(acc, z0, scale);
    passC_kernel<<<dim3(13, BB), blk, 0, stream>>>(I, control, f0, scale);
    passB_kernel<1><<<dim3(8, BB), blk, 0, stream>>>(I, avg_shape, fbins, loc_w, acc, z0);
    passD_kernel<<<dim3(13, BB), blk, 0, stream>>>(I, filtered);
}